// Round 9
// baseline (499.157 us; speedup 1.0000x reference)
//
#include <hip/hip_runtime.h>
#include <hip/hip_bf16.h>

// Problem constants
#define NB   2
#define NC   96
#define NW   128
#define NPIX 16384   // 128*128
#define NHD  8
#define CHD  12
#define HIDC 255
#define H2C  510
#define H4C  1020

typedef __hip_bfloat16 bf16;
typedef unsigned short u16;
typedef unsigned int   u32;

typedef __attribute__((ext_vector_type(8))) __bf16 bfrag;
typedef __attribute__((ext_vector_type(4))) float  ffrag;

__device__ __forceinline__ float bfu(u16 u)  { return __uint_as_float(((u32)u) << 16); }
__device__ __forceinline__ float bflo(u32 u) { return __uint_as_float(u << 16); }
__device__ __forceinline__ float bfhi(u32 u) { return __uint_as_float(u & 0xffff0000u); }
__device__ __forceinline__ u16 f2u16(float a) {
    bf16 x = __float2bfloat16(a); return *(u16*)&x;
}
__device__ __forceinline__ u32 packbf(float a, float b) {
    return (u32)f2u16(a) | ((u32)f2u16(b) << 16);
}
__device__ __forceinline__ uint4 pack8(const float o[8]) {
    uint4 r; r.x = packbf(o[0], o[1]); r.y = packbf(o[2], o[3]);
    r.z = packbf(o[4], o[5]); r.w = packbf(o[6], o[7]); return r;
}

// ---- LDS row layout: [8-u16 halo chunk][128 data], stride LSTR=136 u16.
// Left halo (col -1) at idx 7; right halo (col 128) at idx 136 (next row's chunk-0
// word-0). Window reads = 3 aligned ds_read_b128.
#define LSTR 136
__device__ __forceinline__ void lrow10(const u16* rowbase, int seg, float a[10]) {
    const uint4* q = (const uint4*)(rowbase + seg * 8);
    uint4 vL = q[0], v = q[1], vR = q[2];
    a[0] = bfhi(vL.w);
    a[1] = bflo(v.x); a[2] = bfhi(v.x); a[3] = bflo(v.y); a[4] = bfhi(v.y);
    a[5] = bflo(v.z); a[6] = bfhi(v.z); a[7] = bflo(v.w); a[8] = bfhi(v.w);
    a[9] = bflo(vR.x);
}

__device__ __forceinline__ void conv3r(const float a0[10], const float a1[10],
                                       const float a2[10], const float* w9, float o[8]) {
    #pragma unroll
    for (int j = 0; j < 8; ++j) {
        float v = 0.f;
        #pragma unroll
        for (int d = 0; d < 3; ++d)
            v += w9[d] * a0[j + d] + w9[3 + d] * a1[j + d] + w9[6 + d] * a2[j + d];
        o[j] = v;
    }
}

// ================= fused FFN midsection (2-row work items) =================
// yi --main dw+relu--> ym --box(replicate)--> l, hb=ym-l --lp/hp dw+relu-->
// lp,hp --ld/hd(4->1)+relu--> cat. Block = (8-row tile, group g, batch).
__global__ __launch_bounds__(256) void ffnmid_kernel(
    const u16* __restrict__ yi, const float* __restrict__ main_w,
    const float* __restrict__ lp_w, const float* __restrict__ hp_w,
    const float* __restrict__ ld_w, const float* __restrict__ hd_w,
    u16* __restrict__ cat) {
    // u16 offsets (16B aligned). yis aliased with lps/hps (disjoint lifetimes).
    const int oLPS = 0;       // [4][10][LSTR]+8 = 5448
    const int oHPS = 5448;    // -> 10896
    const int oYIS = 0;       // [2][16][LSTR]+8 = 4360 (dead after S2)
    const int oYMS = 10896;   // [4][14][LSTR]+8 = 7624 -> 18520
    const int oLLS = 18520;   // [4][12][LSTR]+8 = 6536 -> 25056
    const int oHBS = 25056;   // [4][12][LSTR]+8 = 6536 -> 31592
    __shared__ __align__(16) u16 lds[31600];
    __shared__ float wts[180];  // [main 36][lp 36][hp 36][ld 36][hd 36]

    int g  = blockIdx.y;
    int y0 = blockIdx.x * 8;
    int tid = threadIdx.x;
    const u16* yib = yi + (size_t)blockIdx.z * H2C * NPIX;
    u16* catb = cat + (size_t)blockIdx.z * H2C * NPIX;

    if (tid < 180) {
        int idx = tid; float v;
        if (idx < 36)       v = main_w[(4 * g) * 9 + idx];
        else if (idx < 72)  v = lp_w[(4 * g) * 9 + (idx - 36)];
        else if (idx < 108) v = hp_w[(4 * g) * 9 + (idx - 72)];
        else if (idx < 144) v = ld_w[g * 36 + (idx - 108)];
        else                v = hd_w[g * 36 + (idx - 144)];
        wts[idx] = v;
    }
    {
        u32* z = (u32*)&lds[oYIS];
        #pragma unroll
        for (int k = 0; k < 9; ++k) {
            int i = tid + k * 256;
            if (i < 2180) z[i] = 0;
        }
    }
    __syncthreads();
    // ---- S1: stage yi (2 ch x 16 rows, image rows y0-4 .. y0+11, zero-padded) ----
    #pragma unroll
    for (int k = 0; k < 2; ++k) {
        int t = tid + k * 256;
        int seg = t & 15, s = (t >> 4) & 15, lc = t >> 8;
        int row = y0 - 4 + s;
        if ((unsigned)row < 128u) {
            uint4 v = *(const uint4*)(yib + (size_t)(2 * g + lc) * NPIX + row * NW + seg * 8);
            *(uint4*)&lds[oYIS + (lc * 16 + s) * LSTR + 8 + seg * 8] = v;
        }
    }
    __syncthreads();
    // ---- S2: ym = relu(main conv, zero pad); 2 rows/item; replicate col halos ----
    for (int t = tid; t < 448; t += 256) {
        int seg = t & 15; int u = t >> 4; int p = u % 7, ii = u / 7;
        int ra = y0 - 3 + 2 * p;
        int lc = ii >> 1;
        const u16* yb = &lds[oYIS + (lc * 16 + 2 * p) * LSTR];
        float a0[10], a1[10], a2[10], a3[10];
        lrow10(yb,            seg, a0);
        lrow10(yb + LSTR,     seg, a1);
        lrow10(yb + 2 * LSTR, seg, a2);
        lrow10(yb + 3 * LSTR, seg, a3);
        const float* w9 = &wts[ii * 9];
        float oa[8], ob[8];
        conv3r(a0, a1, a2, w9, oa);
        conv3r(a1, a2, a3, w9, ob);
        if ((unsigned)ra < 128u) {
            #pragma unroll
            for (int j = 0; j < 8; ++j) oa[j] = fmaxf(oa[j], 0.f);
            u16* ymr = &lds[oYMS + (ii * 14 + 2 * p) * LSTR];
            *(uint4*)(ymr + 8 + seg * 8) = pack8(oa);
            if (seg == 0)  ymr[7]   = f2u16(oa[0]);
            if (seg == 15) ymr[136] = f2u16(oa[7]);
        }
        if ((unsigned)(ra + 1) < 128u) {
            #pragma unroll
            for (int j = 0; j < 8; ++j) ob[j] = fmaxf(ob[j], 0.f);
            u16* ymr = &lds[oYMS + (ii * 14 + 2 * p + 1) * LSTR];
            *(uint4*)(ymr + 8 + seg * 8) = pack8(ob);
            if (seg == 0)  ymr[7]   = f2u16(ob[0]);
            if (seg == 15) ymr[136] = f2u16(ob[7]);
        }
    }
    __syncthreads();
    // ---- S3: l = box3x3(ym) replicate pad; hb = ym - l; 2 rows/item ----
    for (int t = tid; t < 384; t += 256) {
        int seg = t & 15; int u = t >> 4; int p = u % 6, ii = u / 6;
        int ra = y0 - 2 + 2 * p, rb = ra + 1;
        const u16* ymb = &lds[oYMS + (ii * 14) * LSTR];
        int A  = min(max(ra - 1, 0), 127) - (y0 - 3);
        int Bi = min(max(ra,     0), 127) - (y0 - 3);
        int Ci = min(max(rb,     0), 127) - (y0 - 3);
        int D  = min(max(rb + 1, 0), 127) - (y0 - 3);
        float aA[10], aB[10], aC[10], aD[10];
        lrow10(ymb + A  * LSTR, seg, aA);
        lrow10(ymb + Bi * LSTR, seg, aB);
        lrow10(ymb + Ci * LSTR, seg, aC);
        lrow10(ymb + D  * LSTR, seg, aD);
        float csa[10], csb[10];
        #pragma unroll
        for (int n = 0; n < 10; ++n) {
            csa[n] = aA[n] + aB[n] + aC[n];
            csb[n] = aB[n] + aC[n] + aD[n];
        }
        uint4 la4 = make_uint4(0,0,0,0), ha4 = make_uint4(0,0,0,0);
        uint4 lb4 = make_uint4(0,0,0,0), hb4 = make_uint4(0,0,0,0);
        if ((unsigned)ra < 128u) {
            float lo[8], ho[8];
            #pragma unroll
            for (int j = 0; j < 8; ++j) {
                float lv = (csa[j] + csa[j + 1] + csa[j + 2]) * (1.f / 9.f);
                lo[j] = lv; ho[j] = aB[j + 1] - lv;
            }
            la4 = pack8(lo); ha4 = pack8(ho);
        }
        if ((unsigned)rb < 128u) {
            float lo[8], ho[8];
            #pragma unroll
            for (int j = 0; j < 8; ++j) {
                float lv = (csb[j] + csb[j + 1] + csb[j + 2]) * (1.f / 9.f);
                lo[j] = lv; ho[j] = aC[j + 1] - lv;
            }
            lb4 = pack8(lo); hb4 = pack8(ho);
        }
        u16* llr = &lds[oLLS + (ii * 12 + 2 * p) * LSTR];
        u16* hbr = &lds[oHBS + (ii * 12 + 2 * p) * LSTR];
        *(uint4*)(llr + 8 + seg * 8) = la4;
        *(uint4*)(llr + LSTR + 8 + seg * 8) = lb4;
        *(uint4*)(hbr + 8 + seg * 8) = ha4;
        *(uint4*)(hbr + LSTR + 8 + seg * 8) = hb4;
        if (seg == 0)  { llr[7] = 0; llr[LSTR + 7] = 0; hbr[7] = 0; hbr[LSTR + 7] = 0; }
        if (seg == 15) { llr[136] = 0; llr[LSTR + 136] = 0; hbr[136] = 0; hbr[LSTR + 136] = 0; }
    }
    __syncthreads();
    // ---- S4: lp = relu(conv(l)); hp = relu(conv(hb)); 2 rows/item, zero pad ----
    for (int t = tid; t < 640; t += 256) {
        int kind = t >= 320;
        int r = t - (kind ? 320 : 0);
        int seg = r & 15; int u = r >> 4; int p = u % 5, ii = u / 5;
        int oa = y0 - 1 + 2 * p;
        const u16* sb = &lds[(kind ? oHBS : oLLS) + (ii * 12 + 2 * p) * LSTR];
        float a0[10], a1[10], a2[10], a3[10];
        lrow10(sb,            seg, a0);
        lrow10(sb + LSTR,     seg, a1);
        lrow10(sb + 2 * LSTR, seg, a2);
        lrow10(sb + 3 * LSTR, seg, a3);
        const float* w9 = &wts[(kind ? 72 : 36) + ii * 9];
        float va[8], vb[8];
        conv3r(a0, a1, a2, w9, va);
        conv3r(a1, a2, a3, w9, vb);
        uint4 oa4 = make_uint4(0,0,0,0), ob4 = make_uint4(0,0,0,0);
        if ((unsigned)oa < 128u) {
            float oo[8];
            #pragma unroll
            for (int j = 0; j < 8; ++j) oo[j] = fmaxf(va[j], 0.f);
            oa4 = pack8(oo);
        }
        if ((unsigned)(oa + 1) < 128u) {
            float oo[8];
            #pragma unroll
            for (int j = 0; j < 8; ++j) oo[j] = fmaxf(vb[j], 0.f);
            ob4 = pack8(oo);
        }
        u16* dst = &lds[(kind ? oHPS : oLPS) + (ii * 10 + 2 * p) * LSTR];
        *(uint4*)(dst + 8 + seg * 8) = oa4;
        *(uint4*)(dst + LSTR + 8 + seg * 8) = ob4;
        if (seg == 0)  { dst[7] = 0; dst[LSTR + 7] = 0; }
        if (seg == 15) { dst[136] = 0; dst[LSTR + 136] = 0; }
    }
    __syncthreads();
    // ---- S5: ld & hd (4->1 grouped conv, zero pad), 2 rows/item -> cat ----
    if (tid < 128) {
        int kind = tid >> 6; int r = tid & 63;
        int p = (r >> 4) & 3, seg = r & 15;
        int ro = y0 + 2 * p;
        const float* w36 = &wts[kind ? 144 : 108];
        float oa[8] = {0.f,0.f,0.f,0.f,0.f,0.f,0.f,0.f};
        float ob[8] = {0.f,0.f,0.f,0.f,0.f,0.f,0.f,0.f};
        #pragma unroll
        for (int ii = 0; ii < 4; ++ii) {
            int ch = 4 * g + ii;
            bool uselp = (ch < H2C) == (kind == 0);
            const u16* rb = &lds[(uselp ? oLPS : oHPS) + (ii * 10 + 2 * p) * LSTR];
            float a0[10], a1[10], a2[10], a3[10];
            lrow10(rb,            seg, a0);
            lrow10(rb + LSTR,     seg, a1);
            lrow10(rb + 2 * LSTR, seg, a2);
            lrow10(rb + 3 * LSTR, seg, a3);
            const float* w9 = &w36[ii * 9];
            float va[8], vb[8];
            conv3r(a0, a1, a2, w9, va);
            conv3r(a1, a2, a3, w9, vb);
            #pragma unroll
            for (int j = 0; j < 8; ++j) { oa[j] += va[j]; ob[j] += vb[j]; }
        }
        float xa[8], xb[8];
        #pragma unroll
        for (int j = 0; j < 8; ++j) { xa[j] = fmaxf(oa[j], 0.f); xb[j] = fmaxf(ob[j], 0.f); }
        int cc = kind ? (HIDC + g) : g;
        u16* op = catb + (size_t)cc * NPIX + ro * NW + seg * 8;
        *(uint4*)op = pack8(xa);
        *(uint4*)(op + NW) = pack8(xb);
    }
}

// ================= MFMA GEMM for 1x1 convs =================
template <typename TOut, bool RES>
__global__ __launch_bounds__(256) void gemm1x1_kernel(
    const u16* __restrict__ Bm, const float* __restrict__ Am,
    const float* __restrict__ res, TOut* __restrict__ Cm,
    int M, int K, size_t strideB, size_t strideC) {
    __shared__ u16 Ash[64 * 40];
    __shared__ u16 Bsh[128 * 40];
    const u16* Bz = Bm + (size_t)blockIdx.z * strideB;
    int n0 = blockIdx.x * 128;
    int m0 = blockIdx.y * 64;
    int tid = threadIdx.x;
    int w = tid >> 6, l15 = tid & 15, q = (tid & 63) >> 4;
    int amm = tid >> 2, akc = (tid & 3) * 8;
    int bkk = tid >> 3, bs0 = tid & 7;

    ffrag acc[8];
    #pragma unroll
    for (int nt = 0; nt < 8; ++nt)
        #pragma unroll
        for (int e = 0; e < 4; ++e) acc[nt][e] = 0.f;

    for (int k0 = 0; k0 < K; k0 += 32) {
        {
            int gm = m0 + amm;
            float f[8];
            #pragma unroll
            for (int e = 0; e < 8; ++e) {
                int gk = k0 + akc + e;
                f[e] = (gm < M && gk < K) ? Am[(size_t)gm * K + gk] : 0.f;
            }
            u32* dst = (u32*)&Ash[amm * 40 + akc];
            #pragma unroll
            for (int e = 0; e < 4; ++e) dst[e] = packbf(f[2 * e], f[2 * e + 1]);
        }
        {
            int gk = k0 + bkk;
            bool ok = gk < K;
            const u16* src = Bz + (size_t)gk * NPIX + n0;
            #pragma unroll
            for (int pass = 0; pass < 2; ++pass) {
                int nn = (bs0 + pass * 8) * 8;
                if (ok) {
                    uint4 v = *(const uint4*)(src + nn);
                    Bsh[(nn + 0) * 40 + bkk] = (u16)(v.x & 0xffff);
                    Bsh[(nn + 1) * 40 + bkk] = (u16)(v.x >> 16);
                    Bsh[(nn + 2) * 40 + bkk] = (u16)(v.y & 0xffff);
                    Bsh[(nn + 3) * 40 + bkk] = (u16)(v.y >> 16);
                    Bsh[(nn + 4) * 40 + bkk] = (u16)(v.z & 0xffff);
                    Bsh[(nn + 5) * 40 + bkk] = (u16)(v.z >> 16);
                    Bsh[(nn + 6) * 40 + bkk] = (u16)(v.w & 0xffff);
                    Bsh[(nn + 7) * 40 + bkk] = (u16)(v.w >> 16);
                } else {
                    #pragma unroll
                    for (int e = 0; e < 8; ++e) Bsh[(nn + e) * 40 + bkk] = 0;
                }
            }
        }
        __syncthreads();
        bfrag af = *(const bfrag*)&Ash[(w * 16 + l15) * 40 + q * 8];
        #pragma unroll
        for (int nt = 0; nt < 8; ++nt) {
            bfrag bf = *(const bfrag*)&Bsh[(nt * 16 + l15) * 40 + q * 8];
            acc[nt] = __builtin_amdgcn_mfma_f32_16x16x32_bf16(af, bf, acc[nt], 0, 0, 0);
        }
        __syncthreads();
    }
    TOut* Cz = Cm + (size_t)blockIdx.z * strideC;
    const float* rz = res + (RES ? (size_t)blockIdx.z * strideC : 0);
    int mrow = m0 + w * 16 + q * 4;
    #pragma unroll
    for (int nt = 0; nt < 8; ++nt) {
        int col = n0 + nt * 16 + l15;
        #pragma unroll
        for (int r = 0; r < 4; ++r) {
            int row = mrow + r;
            if (row < M) {
                float v = acc[nt][r];
                if (RES) v += rz[(size_t)row * NPIX + col];
                if constexpr (sizeof(TOut) == 2) {
                    ((u16*)Cz)[(size_t)row * NPIX + col] = f2u16(v);
                } else {
                    ((float*)Cz)[(size_t)row * NPIX + col] = v;
                }
            }
        }
    }
}

// ---------------- LayerNorm (fp32 in, bf16 out), channel-split blocks ----------------
__global__ __launch_bounds__(256) void ln_kernel(
    const float* __restrict__ x, const float* __restrict__ g,
    const float* __restrict__ bta, u16* __restrict__ out) {
    int blk = blockIdx.x;
    int b = blk >> 9;
    int p = ((blk & 511) << 5) + (threadIdx.x & 31);
    int cg = threadIdx.x >> 5;
    const float* xb = x + (size_t)b * NC * NPIX + p;
    float v[12]; float s = 0.f, s2 = 0.f;
    #pragma unroll
    for (int j = 0; j < 12; ++j) {
        float t = xb[(size_t)(cg * 12 + j) * NPIX];
        v[j] = t; s += t; s2 += t * t;
    }
    __shared__ float ss[8][32], qq[8][32], smu[32], sinv[32];
    ss[cg][threadIdx.x & 31] = s; qq[cg][threadIdx.x & 31] = s2;
    __syncthreads();
    if (threadIdx.x < 32) {
        float S = 0.f, Q = 0.f;
        #pragma unroll
        for (int k = 0; k < 8; ++k) { S += ss[k][threadIdx.x]; Q += qq[k][threadIdx.x]; }
        float mu = S * (1.f / NC);
        float var = Q * (1.f / NC) - mu * mu;
        smu[threadIdx.x] = mu; sinv[threadIdx.x] = rsqrtf(var + 1e-5f);
    }
    __syncthreads();
    float mu = smu[threadIdx.x & 31], inv = sinv[threadIdx.x & 31];
    u16* ob = out + (size_t)b * NC * NPIX + p;
    #pragma unroll
    for (int j = 0; j < 12; ++j) {
        int c = cg * 12 + j;
        ob[(size_t)c * NPIX] = f2u16((v[j] - mu) * inv * g[c] + bta[c]);
    }
}

// load a 1x10 window row (8 aligned + 2 halo) with zero padding (global memory)
__device__ __forceinline__ void load_row_zpad(const u16* ib, int iy, int x0, float a[10]) {
    if (iy < 0 || iy >= NW) {
        #pragma unroll
        for (int k = 0; k < 10; ++k) a[k] = 0.f;
        return;
    }
    const u16* rp = ib + iy * NW;
    uint4 v = *(const uint4*)(rp + x0);
    a[1]=bflo(v.x); a[2]=bfhi(v.x); a[3]=bflo(v.y); a[4]=bfhi(v.y);
    a[5]=bflo(v.z); a[6]=bfhi(v.z); a[7]=bflo(v.w); a[8]=bfhi(v.w);
    a[0] = (x0 > 0)   ? bfu(rp[x0 - 1]) : 0.f;
    a[9] = (x0 < 120) ? bfu(rp[x0 + 8]) : 0.f;
}

// ---------------- depthwise 3x3 (qkv), zero pad, 4 rows x 8 px/thread ----------------
template <bool RELU>
__global__ __launch_bounds__(256) void dwconv3x3_kernel(
    const u16* __restrict__ in, const float* __restrict__ w,
    u16* __restrict__ out, int CHN, int ICN, int idiv) {
    int id = blockIdx.x * 256 + threadIdx.x;   // 0..511
    int ty = id >> 4, tx = id & 15;
    int y0 = ty * 4, x0 = tx * 8;
    int b = blockIdx.y / CHN, oc = blockIdx.y % CHN;
    int ic = oc / idiv;
    const u16* ib = in + ((size_t)b * ICN + ic) * NPIX;
    float a[6][10];
    #pragma unroll
    for (int k = 0; k < 6; ++k) load_row_zpad(ib, y0 - 1 + k, x0, a[k]);
    const float* wr = w + (size_t)oc * 9;
    float w9[9];
    #pragma unroll
    for (int k = 0; k < 9; ++k) w9[k] = wr[k];
    u16* ob = out + ((size_t)b * CHN + oc) * NPIX + y0 * NW + x0;
    #pragma unroll
    for (int jr = 0; jr < 4; ++jr) {
        float o[8];
        #pragma unroll
        for (int j = 0; j < 8; ++j) {
            float s = 0.f;
            #pragma unroll
            for (int r = 0; r < 3; ++r)
                #pragma unroll
                for (int kx = 0; kx < 3; ++kx)
                    s += w9[r * 3 + kx] * a[jr + r][j + kx];
            o[j] = RELU ? fmaxf(s, 0.f) : s;
        }
        *(uint4*)(ob + jr * NW) = pack8(o);
    }
}

// ---------------- q/k row L2 norms -> reciprocal scales ----------------
__global__ __launch_bounds__(256) void qknorm_kernel(
    const u16* __restrict__ qkv2, float* __restrict__ scales) {
    int r = blockIdx.x;
    int b = r / 192, ch = r % 192;
    const u16* src = qkv2 + ((size_t)b * 288 + ch) * NPIX;
    float s = 0.f;
    for (int p = threadIdx.x * 8; p < NPIX; p += 2048) {
        uint4 v = *(const uint4*)(src + p);
        float f[8];
        f[0]=bflo(v.x); f[1]=bfhi(v.x); f[2]=bflo(v.y); f[3]=bfhi(v.y);
        f[4]=bflo(v.z); f[5]=bfhi(v.z); f[6]=bflo(v.w); f[7]=bfhi(v.w);
        #pragma unroll
        for (int k = 0; k < 8; ++k) s += f[k] * f[k];
    }
    #pragma unroll
    for (int off = 32; off > 0; off >>= 1) s += __shfl_down(s, off, 64);
    __shared__ float part[4];
    int wid = threadIdx.x >> 6;
    if ((threadIdx.x & 63) == 0) part[wid] = s;
    __syncthreads();
    if (threadIdx.x == 0) {
        float tot = part[0] + part[1] + part[2] + part[3];
        scales[r] = 1.f / fmaxf(sqrtf(tot), 1e-12f);
    }
}

// ---------------- raw attn dots, 4-way pixel split + atomicAdd ----------------
__global__ __launch_bounds__(256) void attn_kernel(
    const u16* __restrict__ qkv2, float* __restrict__ attn_raw) {
    int blk = blockIdx.y;  // ((b*NHD+h)*CHD+i)
    int slice = blockIdx.x;
    int i = blk % CHD; int h = (blk / CHD) % NHD; int b = blk / (CHD * NHD);
    const u16* q = qkv2 + ((size_t)b * 288 + h * CHD + i) * NPIX;
    const u16* k = qkv2 + ((size_t)b * 288 + 96 + h * CHD) * NPIX;
    float acc[CHD];
    #pragma unroll
    for (int j = 0; j < CHD; ++j) acc[j] = 0.f;
    int p0 = slice * 4096;
    #pragma unroll
    for (int it = 0; it < 2; ++it) {
        int p = p0 + it * 2048 + threadIdx.x * 8;
        uint4 qv = *(const uint4*)(q + p);
        float qf[8];
        qf[0]=bflo(qv.x); qf[1]=bfhi(qv.x); qf[2]=bflo(qv.y); qf[3]=bfhi(qv.y);
        qf[4]=bflo(qv.z); qf[5]=bfhi(qv.z); qf[6]=bflo(qv.w); qf[7]=bfhi(qv.w);
        #pragma unroll
        for (int j = 0; j < CHD; ++j) {
            uint4 kv = *(const uint4*)(k + (size_t)j * NPIX + p);
            float s = qf[0]*bflo(kv.x) + qf[1]*bfhi(kv.x) + qf[2]*bflo(kv.y) + qf[3]*bfhi(kv.y)
                    + qf[4]*bflo(kv.z) + qf[5]*bfhi(kv.z) + qf[6]*bflo(kv.w) + qf[7]*bfhi(kv.w);
            acc[j] += s;
        }
    }
    __shared__ float part[4][CHD];
    int wid = threadIdx.x >> 6, lane = threadIdx.x & 63;
    #pragma unroll
    for (int j = 0; j < CHD; ++j) {
        float v = acc[j];
        #pragma unroll
        for (int off = 32; off > 0; off >>= 1) v += __shfl_down(v, off, 64);
        if (lane == 0) part[wid][j] = v;
    }
    __syncthreads();
    if (threadIdx.x < CHD) {
        int j = threadIdx.x;
        float d = part[0][j] + part[1][j] + part[2][j] + part[3][j];
        atomicAdd(&attn_raw[(size_t)blk * CHD + j], d);
    }
}

// ---------------- STS: scale raw dots, thresholds, softmax mix ----------------
__global__ __launch_bounds__(256) void sts_kernel(
    const float* __restrict__ attn, const float* __restrict__ scl,
    const float* __restrict__ temp, const float* __restrict__ tw,
    const float* __restrict__ w1, const float* __restrict__ b1,
    const float* __restrict__ w2, const float* __restrict__ b2,
    float* __restrict__ attn_c) {
    int b = blockIdx.x;
    __shared__ float sat[NHD * CHD * CHD];
    __shared__ float avg[NHD];
    __shared__ float thr[4][NHD];
    for (int idx = threadIdx.x; idx < NHD * CHD * CHD; idx += 256) {
        int h = idx / (CHD * CHD); int r = idx % (CHD * CHD);
        int i = r / CHD, j = r % CHD;
        sat[idx] = attn[(size_t)b * NHD * CHD * CHD + idx]
                 * scl[b * 192 + h * CHD + i] * scl[b * 192 + 96 + h * CHD + j] * temp[h];
    }
    __syncthreads();
    if (threadIdx.x < NHD) {
        float s = 0.f;
        for (int t = 0; t < CHD * CHD; ++t) s += fabsf(sat[threadIdx.x * CHD * CHD + t]);
        avg[threadIdx.x] = s * (1.f / (CHD * CHD));
    }
    __syncthreads();
    if (threadIdx.x < 4) {
        int s = threadIdx.x;
        float t1[NHD];
        for (int hp = 0; hp < NHD; ++hp) {
            float u = b1[s * NHD + hp];
            for (int h = 0; h < NHD; ++h) u += avg[h] * w1[s * 64 + hp * NHD + h];
            t1[hp] = fmaxf(u, 0.f);
        }
        for (int hp = 0; hp < NHD; ++hp) {
            float u = b2[s * NHD + hp];
            for (int h = 0; h < NHD; ++h) u += t1[h] * w2[s * 64 + hp * NHD + h];
            float gg = 1.f / (1.f + expf(-u));
            thr[s][hp] = avg[hp] * gg;
        }
    }
    __syncthreads();
    if (threadIdx.x < NHD * CHD) {
        int h = threadIdx.x / CHD, i = threadIdx.x % CHD;
        const float* arow = sat + (h * CHD + i) * CHD;
        float acc[CHD];
        #pragma unroll
        for (int j = 0; j < CHD; ++j) acc[j] = 0.f;
        for (int s = 0; s < 4; ++s) {
            float comp[CHD]; float m = -1e30f;
            #pragma unroll
            for (int j = 0; j < CHD; ++j) {
                float a = arow[j];
                float sg = (a > 0.f) ? 1.f : ((a < 0.f) ? -1.f : 0.f);
                float c = sg * fmaxf(fabsf(a) - thr[s][h], 0.f);
                comp[j] = c; m = fmaxf(m, c);
            }
            float sum = 0.f;
            #pragma unroll
            for (int j = 0; j < CHD; ++j) { comp[j] = expf(comp[j] - m); sum += comp[j]; }
            float wts2 = tw[s] / sum;
            #pragma unroll
            for (int j = 0; j < CHD; ++j) acc[j] += wts2 * comp[j];
        }
        for (int j = 0; j < CHD; ++j)
            attn_c[(size_t)b * NHD * CHD * CHD + (h * CHD + i) * CHD + j] = acc[j];
    }
}

// ---------------- out = attn_c @ v, 4 px/thread, bf16 out ----------------
__global__ __launch_bounds__(256) void av_kernel(
    const float* __restrict__ attn_c, const u16* __restrict__ qkv2,
    u16* __restrict__ outv) {
    int p0 = (blockIdx.x * 256 + threadIdx.x) * 4;
    int bc = blockIdx.y;
    int b = bc / NC, hc = bc % NC; int h = hc / CHD, i = hc % CHD;
    const float* a = attn_c + ((size_t)(b * NHD + h) * CHD + i) * CHD;
    const u16* v = qkv2 + ((size_t)b * 288 + 192 + h * CHD) * NPIX;
    float av[CHD];
    #pragma unroll
    for (int j = 0; j < CHD; ++j) av[j] = a[j];
    float o[4] = {0.f, 0.f, 0.f, 0.f};
    #pragma unroll
    for (int j = 0; j < CHD; ++j) {
        uint2 t = *(const uint2*)(v + (size_t)j * NPIX + p0);
        o[0] += av[j] * bflo(t.x); o[1] += av[j] * bfhi(t.x);
        o[2] += av[j] * bflo(t.y); o[3] += av[j] * bfhi(t.y);
    }
    uint2 t; t.x = packbf(o[0], o[1]); t.y = packbf(o[2], o[3]);
    *(uint2*)(outv + ((size_t)b * NC + hc) * NPIX + p0) = t;
}

// ---------------- launch ----------------
extern "C" void kernel_launch(void* const* d_in, const int* in_sizes, int n_in,
                              void* d_out, int out_size, void* d_ws, size_t ws_size,
                              hipStream_t stream) {
    const float* x       = (const float*)d_in[0];
    const float* norm1_w = (const float*)d_in[1];
    const float* norm1_b = (const float*)d_in[2];
    const float* qkv_w   = (const float*)d_in[3];
    const float* qkv_dw  = (const float*)d_in[4];
    const float* proj_w  = (const float*)d_in[5];
    const float* temp    = (const float*)d_in[6];
    const float* thw     = (const float*)d_in[7];
    const float* aw1     = (const float*)d_in[8];
    const float* ab1     = (const float*)d_in[9];
    const float* aw2     = (const float*)d_in[10];
    const float* ab2     = (const float*)d_in[11];
    const float* norm2_w = (const float*)d_in[12];
    const float* norm2_b = (const float*)d_in[13];
    const float* in_w    = (const float*)d_in[14];
    const float* main_w  = (const float*)d_in[15];
    const float* lp_w    = (const float*)d_in[16];
    const float* hp_w    = (const float*)d_in[17];
    const float* ld_w    = (const float*)d_in[18];
    const float* hd_w    = (const float*)d_in[19];
    const float* out_w   = (const float*)d_in[20];
    float* out = (float*)d_out;

    // ---- workspace layout ----
    char* ws = (char*)d_ws;
    float* x1    = (float*)(ws + 0);            // 12,582,912 fp32 residual stream
    u16*   xnb   = (u16*)(ws + 12582912);       // 6,291,456  bf16 LN/attn-out
    u16*   qkv1  = (u16*)(ws + 18874368);       // 18,874,368 bf16 [2][288][NPIX]
    u16*   qkv2  = (u16*)(ws + 37748736);       // 18,874,368 bf16 [2][288][NPIX]
    float* scl   = (float*)(ws + 56623104);
    float* attn  = (float*)(ws + 56639488);
    float* attnc = (float*)(ws + 56655872);
    char*  F0    = ws + 56672256;
    const size_t S_full = 33423360;
    bool full = ws_size >= (size_t)56672256 + S_full;   // 90,095,616

    dim3 blk(256);
    // ---- attention half ----
    ln_kernel<<<dim3(NB * NPIX / 32), blk, 0, stream>>>(x, norm1_w, norm1_b, xnb);
    gemm1x1_kernel<u16, false><<<dim3(128, 5, NB), blk, 0, stream>>>(
        xnb, qkv_w, nullptr, qkv1, 288, 96, (size_t)NC * NPIX, (size_t)288 * NPIX);
    dwconv3x3_kernel<false><<<dim3(2, NB * 288), blk, 0, stream>>>(
        qkv1, qkv_dw, qkv2, 288, 288, 1);
    qknorm_kernel<<<dim3(NB * 192), blk, 0, stream>>>(qkv2, scl);
    hipMemsetAsync(attn, 0, (size_t)NB * NHD * CHD * CHD * sizeof(float), stream);
    attn_kernel<<<dim3(4, NB * NHD * CHD), blk, 0, stream>>>(qkv2, attn);
    sts_kernel<<<dim3(NB), blk, 0, stream>>>(attn, scl, temp, thw, aw1, ab1, aw2, ab2, attnc);
    av_kernel<<<dim3(16, NB * NC), blk, 0, stream>>>(attnc, qkv2, xnb);
    gemm1x1_kernel<float, true><<<dim3(128, 2, NB), blk, 0, stream>>>(
        xnb, proj_w, x, x1, 96, 96, (size_t)NC * NPIX, (size_t)NC * NPIX);
    // ---- FFN half ----
    ln_kernel<<<dim3(NB * NPIX / 32), blk, 0, stream>>>(x1, norm2_w, norm2_b, xnb);
    if (full) {
        u16* yi  = qkv1;     // 33.4 MB spanning qkv1+qkv2 (dead now)
        u16* cat = (u16*)F0;
        gemm1x1_kernel<u16, false><<<dim3(128, 8, NB), blk, 0, stream>>>(
            xnb, in_w, nullptr, yi, H2C, 96, (size_t)NC * NPIX, (size_t)H2C * NPIX);
        ffnmid_kernel<<<dim3(16, HIDC, NB), blk, 0, stream>>>(
            yi, main_w, lp_w, hp_w, ld_w, hd_w, cat);
        gemm1x1_kernel<float, true><<<dim3(128, 2, NB), blk, 0, stream>>>(
            cat, out_w, x1, out, 96, H2C, (size_t)H2C * NPIX, (size_t)NC * NPIX);
    } else {
        for (int b = 0; b < NB; ++b) {
            u16* yi  = qkv1;
            u16* cat = qkv2;
            gemm1x1_kernel<u16, false><<<dim3(128, 8, 1), blk, 0, stream>>>(
                xnb + (size_t)b * NC * NPIX, in_w, nullptr, yi, H2C, 96, 0, 0);
            ffnmid_kernel<<<dim3(16, HIDC, 1), blk, 0, stream>>>(
                yi, main_w, lp_w, hp_w, ld_w, hd_w, cat);
            gemm1x1_kernel<float, true><<<dim3(128, 2, 1), blk, 0, stream>>>(
                cat, out_w, x1 + (size_t)b * NC * NPIX, out + (size_t)b * NC * NPIX,
                96, H2C, 0, 0);
        }
    }
}

// Round 11
// 477.153 us; speedup vs baseline: 1.0461x; 1.0461x over previous
//
#include <hip/hip_runtime.h>
#include <hip/hip_bf16.h>
#include <hip/hip_fp16.h>

// Problem constants
#define NB   2
#define NC   96
#define NW   128
#define NPIX 16384   // 128*128
#define NHD  8
#define CHD  12
#define HIDC 255
#define H2C  510
#define H4C  1020

typedef __hip_bfloat16 bf16;
typedef unsigned short u16;
typedef unsigned int   u32;
typedef __half2 h2t;

typedef __attribute__((ext_vector_type(8))) __bf16 bfrag;
typedef __attribute__((ext_vector_type(4))) float  ffrag;

__device__ __forceinline__ float bfu(u16 u)  { return __uint_as_float(((u32)u) << 16); }
__device__ __forceinline__ float bflo(u32 u) { return __uint_as_float(u << 16); }
__device__ __forceinline__ float bfhi(u32 u) { return __uint_as_float(u & 0xffff0000u); }
__device__ __forceinline__ u16 f2u16(float a) {
    bf16 x = __float2bfloat16(a); return *(u16*)&x;
}
__device__ __forceinline__ u32 packbf(float a, float b) {
    return (u32)f2u16(a) | ((u32)f2u16(b) << 16);
}
__device__ __forceinline__ uint4 pack8(const float o[8]) {
    uint4 r; r.x = packbf(o[0], o[1]); r.y = packbf(o[2], o[3]);
    r.z = packbf(o[4], o[5]); r.w = packbf(o[6], o[7]); return r;
}

// half2 bit helpers
__device__ __forceinline__ h2t H2u(u32 v) { return __builtin_bit_cast(h2t, v); }
__device__ __forceinline__ u32 U32h(h2t v) { return __builtin_bit_cast(u32, v); }
// (lo.hi, hi.lo) pair — compiler lowers to v_alignbit
__device__ __forceinline__ u32 abit(u32 hi, u32 lo) { return (lo >> 16) | (hi << 16); }
// branch-free per-lane fp16 relu (sign bit set -> 0); avoids missing __hmax2(half2)
__device__ __forceinline__ h2t relu2(h2t v) {
    u32 u = U32h(v);
    u32 lo = (u & 0x8000u)     ? 0u : (u & 0xFFFFu);
    u32 hi = (u & 0x80000000u) ? 0u : (u & 0xFFFF0000u);
    return H2u(lo | hi);
}

// ---- LDS row layout: [8-u16 halo chunk][128 data], stride LSTR=136 u16.
// Left halo (col -1) at idx 7; right halo (col 128) at idx 136 (next row's chunk-0
// word-0). Window reads = 3 aligned ds_read_b128.
#define LSTR 136

// packed row window: 4 center pairs + 5 shifted pairs
struct Row { h2t c0, c1, c2, c3, l0, l1, l2, l3, l4; };
__device__ __forceinline__ Row loadrow(const u16* rb, int seg) {
    const uint4* q = (const uint4*)(rb + seg * 8);
    uint4 a = q[0], v = q[1], b = q[2];
    Row r;
    r.c0 = H2u(v.x); r.c1 = H2u(v.y); r.c2 = H2u(v.z); r.c3 = H2u(v.w);
    r.l0 = H2u(abit(v.x, a.w)); r.l1 = H2u(abit(v.y, v.x)); r.l2 = H2u(abit(v.z, v.y));
    r.l3 = H2u(abit(v.w, v.z)); r.l4 = H2u(abit(b.x, v.w));
    return r;
}
// 3-tap horizontal conv accumulate: 12 pk-fma
__device__ __forceinline__ void cacc(const Row& r, h2t w0, h2t w1, h2t w2, h2t o[4]) {
    o[0] = __hfma2(w0, r.l0, __hfma2(w1, r.c0, __hfma2(w2, r.l1, o[0])));
    o[1] = __hfma2(w0, r.l1, __hfma2(w1, r.c1, __hfma2(w2, r.l2, o[1])));
    o[2] = __hfma2(w0, r.l2, __hfma2(w1, r.c2, __hfma2(w2, r.l3, o[2])));
    o[3] = __hfma2(w0, r.l3, __hfma2(w1, r.c3, __hfma2(w2, r.l4, o[3])));
}
// raw dwords of a row window (for box filter vertical sums incl. halo cols)
struct Raw { u32 w0; uint4 v; u32 r0; };
__device__ __forceinline__ Raw ldraw(const u16* rb, int seg) {
    const uint4* q = (const uint4*)(rb + seg * 8);
    Raw r; uint4 a = q[0]; r.w0 = a.w; r.v = q[1]; r.r0 = q[2].x; return r;
}

// ================= fused FFN midsection (fp16 packed math) =================
// yi(fp16) --main dw+relu--> ym --box(replicate)--> l, hb=ym-l --lp/hp dw+relu-->
// lp,hp --ld/hd(4->1)+relu--> cat(bf16). Block = (8-row tile, group g, batch).
__global__ __launch_bounds__(256) void ffnmid_kernel(
    const u16* __restrict__ yi, const float* __restrict__ main_w,
    const float* __restrict__ lp_w, const float* __restrict__ hp_w,
    const float* __restrict__ ld_w, const float* __restrict__ hd_w,
    u16* __restrict__ cat) {
    const int oLPS = 0;       // [4][10][LSTR]+8 = 5448
    const int oHPS = 5448;    // -> 10896
    const int oYIS = 0;       // [2][16][LSTR]+8 = 4360 (dead after S2)
    const int oYMS = 10896;   // [4][14][LSTR]+8 = 7624 -> 18520
    const int oLLS = 18520;   // [4][12][LSTR]+8 = 6536 -> 25056
    const int oHBS = 25056;   // [4][12][LSTR]+8 = 6536 -> 31592
    __shared__ __align__(16) u16 lds[31600];
    __shared__ u32 wts2[180];  // duplicated-fp16 weights [main 36][lp 36][hp 36][ld 36][hd 36]

    int g  = blockIdx.y;
    int y0 = blockIdx.x * 8;
    int tid = threadIdx.x;
    const u16* yib = yi + (size_t)blockIdx.z * H2C * NPIX;
    u16* catb = cat + (size_t)blockIdx.z * H2C * NPIX;

    if (tid < 180) {
        int idx = tid; float v;
        if (idx < 36)       v = main_w[(4 * g) * 9 + idx];
        else if (idx < 72)  v = lp_w[(4 * g) * 9 + (idx - 36)];
        else if (idx < 108) v = hp_w[(4 * g) * 9 + (idx - 72)];
        else if (idx < 144) v = ld_w[g * 36 + (idx - 108)];
        else                v = hd_w[g * 36 + (idx - 144)];
        __half hh = __float2half(v);
        u16 hb16 = __builtin_bit_cast(u16, hh);
        wts2[idx] = (u32)hb16 * 0x10001u;
    }
    {
        u32* z = (u32*)&lds[oYIS];
        #pragma unroll
        for (int k = 0; k < 9; ++k) {
            int i = tid + k * 256;
            if (i < 2180) z[i] = 0;
        }
    }
    __syncthreads();
    // ---- S1: stage yi (fp16, 2 ch x 16 rows, image rows y0-4..y0+11, zero-pad) ----
    #pragma unroll
    for (int k = 0; k < 2; ++k) {
        int t = tid + k * 256;
        int seg = t & 15, s = (t >> 4) & 15, lc = t >> 8;
        int row = y0 - 4 + s;
        if ((unsigned)row < 128u) {
            uint4 v = *(const uint4*)(yib + (size_t)(2 * g + lc) * NPIX + row * NW + seg * 8);
            *(uint4*)&lds[oYIS + (lc * 16 + s) * LSTR + 8 + seg * 8] = v;
        }
    }
    __syncthreads();
    h2t z2 = H2u(0u);
    // ---- S2: ym = relu(main conv, zero pad); replicate col halos ----
    for (int t = tid; t < 896; t += 256) {
        int seg = t & 15; int u = t >> 4; int s = u % 14, ii = u / 14;
        int row = y0 - 3 + s;
        if ((unsigned)row >= 128u) continue;  // out-of-image ym rows never read
        int lc = ii >> 1;
        const u16* yb = &lds[oYIS + (lc * 16 + s) * LSTR];
        Row r0 = loadrow(yb, seg), r1 = loadrow(yb + LSTR, seg), r2 = loadrow(yb + 2 * LSTR, seg);
        h2t o[4] = {z2, z2, z2, z2};
        cacc(r0, H2u(wts2[ii*9+0]), H2u(wts2[ii*9+1]), H2u(wts2[ii*9+2]), o);
        cacc(r1, H2u(wts2[ii*9+3]), H2u(wts2[ii*9+4]), H2u(wts2[ii*9+5]), o);
        cacc(r2, H2u(wts2[ii*9+6]), H2u(wts2[ii*9+7]), H2u(wts2[ii*9+8]), o);
        #pragma unroll
        for (int k = 0; k < 4; ++k) o[k] = relu2(o[k]);
        u16* ymr = &lds[oYMS + (ii * 14 + s) * LSTR];
        uint4 st; st.x = U32h(o[0]); st.y = U32h(o[1]); st.z = U32h(o[2]); st.w = U32h(o[3]);
        *(uint4*)(ymr + 8 + seg * 8) = st;
        if (seg == 0)  ymr[7]   = (u16)(st.x & 0xffff);   // replicate left halo
        if (seg == 15) ymr[136] = (u16)(st.w >> 16);      // replicate right halo
    }
    __syncthreads();
    // ---- S3: l = box3x3(ym) replicate pad; hb = ym - l; zero outside image ----
    for (int t = tid; t < 768; t += 256) {
        int seg = t & 15; int u = t >> 4; int s = u % 12, ii = u / 12;
        int row = y0 - 2 + s;
        u16* llr = &lds[oLLS + (ii * 12 + s) * LSTR];
        u16* hbr = &lds[oHBS + (ii * 12 + s) * LSTR];
        uint4 lst = make_uint4(0, 0, 0, 0), hst = make_uint4(0, 0, 0, 0);
        if ((unsigned)row < 128u) {
            int r0 = min(max(row - 1, 0), 127) - (y0 - 3);
            int r1 = row - (y0 - 3);
            int r2 = min(max(row + 1, 0), 127) - (y0 - 3);
            const u16* ymb = &lds[oYMS + (ii * 14) * LSTR];
            Raw A = ldraw(ymb + r0 * LSTR, seg);
            Raw B = ldraw(ymb + r1 * LSTR, seg);
            Raw C = ldraw(ymb + r2 * LSTR, seg);
            // vertical sums (pairs), incl. halo cols
            h2t sW = __hadd2(__hadd2(H2u(A.w0), H2u(B.w0)), H2u(C.w0));
            h2t sx = __hadd2(__hadd2(H2u(A.v.x), H2u(B.v.x)), H2u(C.v.x));
            h2t sy = __hadd2(__hadd2(H2u(A.v.y), H2u(B.v.y)), H2u(C.v.y));
            h2t sz = __hadd2(__hadd2(H2u(A.v.z), H2u(B.v.z)), H2u(C.v.z));
            h2t sw = __hadd2(__hadd2(H2u(A.v.w), H2u(B.v.w)), H2u(C.v.w));
            h2t sR = __hadd2(__hadd2(H2u(A.r0), H2u(B.r0)), H2u(C.r0));
            u32 bW = U32h(sW), bx = U32h(sx), by = U32h(sy), bz = U32h(sz),
                bw = U32h(sw), bR = U32h(sR);
            h2t L0 = H2u(abit(bx, bW)), L1 = H2u(abit(by, bx)), L2 = H2u(abit(bz, by)),
                L3 = H2u(abit(bw, bz)), L4 = H2u(abit(bR, bw));
            __half k9h = __float2half(1.f / 9.f);
            h2t k9 = __halves2half2(k9h, k9h);
            h2t l0 = __hmul2(__hadd2(__hadd2(L0, sx), L1), k9);
            h2t l1 = __hmul2(__hadd2(__hadd2(L1, sy), L2), k9);
            h2t l2 = __hmul2(__hadd2(__hadd2(L2, sz), L3), k9);
            h2t l3 = __hmul2(__hadd2(__hadd2(L3, sw), L4), k9);
            h2t h0 = __hsub2(H2u(B.v.x), l0);
            h2t h1 = __hsub2(H2u(B.v.y), l1);
            h2t h2v = __hsub2(H2u(B.v.z), l2);
            h2t h3 = __hsub2(H2u(B.v.w), l3);
            lst.x = U32h(l0); lst.y = U32h(l1); lst.z = U32h(l2); lst.w = U32h(l3);
            hst.x = U32h(h0); hst.y = U32h(h1); hst.z = U32h(h2v); hst.w = U32h(h3);
        }
        *(uint4*)(llr + 8 + seg * 8) = lst;
        *(uint4*)(hbr + 8 + seg * 8) = hst;
        if (seg == 0)  { llr[7] = 0;   hbr[7] = 0; }
        if (seg == 15) { llr[136] = 0; hbr[136] = 0; }
    }
    __syncthreads();
    // ---- S4: lp = relu(conv(l)); hp = relu(conv(hb)) (zero pad) ----
    for (int t = tid; t < 1280; t += 256) {
        int kind = t >= 640;
        int r = t - (kind ? 640 : 0);
        int ii = r / 160; int rem = r - ii * 160;
        int s = rem >> 4, seg = rem & 15;
        int row = y0 - 1 + s;
        u16* dst = &lds[(kind ? oHPS : oLPS) + (ii * 10 + s) * LSTR];
        uint4 st = make_uint4(0, 0, 0, 0);
        if ((unsigned)row < 128u) {
            const u16* sb = &lds[(kind ? oHBS : oLLS) + (ii * 12 + s) * LSTR];
            Row r0 = loadrow(sb, seg), r1 = loadrow(sb + LSTR, seg), r2 = loadrow(sb + 2 * LSTR, seg);
            int wb = (kind ? 72 : 36) + ii * 9;
            h2t o[4] = {z2, z2, z2, z2};
            cacc(r0, H2u(wts2[wb+0]), H2u(wts2[wb+1]), H2u(wts2[wb+2]), o);
            cacc(r1, H2u(wts2[wb+3]), H2u(wts2[wb+4]), H2u(wts2[wb+5]), o);
            cacc(r2, H2u(wts2[wb+6]), H2u(wts2[wb+7]), H2u(wts2[wb+8]), o);
            #pragma unroll
            for (int k = 0; k < 4; ++k) o[k] = relu2(o[k]);
            st.x = U32h(o[0]); st.y = U32h(o[1]); st.z = U32h(o[2]); st.w = U32h(o[3]);
        }
        *(uint4*)(dst + 8 + seg * 8) = st;
        if (seg == 0)  dst[7]   = 0;
        if (seg == 15) dst[136] = 0;
    }
    __syncthreads();
    // ---- S5: ld & hd (4->1 grouped conv, zero pad) -> cat (bf16) ----
    {
        int kind = tid >> 7, s = (tid >> 4) & 7, seg = tid & 15;
        int row = y0 + s;
        int wb = kind ? 144 : 108;
        h2t o[4] = {z2, z2, z2, z2};
        #pragma unroll
        for (int ii = 0; ii < 4; ++ii) {
            int ch = 4 * g + ii;
            bool uselp = (ch < H2C) == (kind == 0);
            const u16* rb = &lds[(uselp ? oLPS : oHPS) + (ii * 10 + s) * LSTR];
            Row r0 = loadrow(rb, seg), r1 = loadrow(rb + LSTR, seg), r2 = loadrow(rb + 2 * LSTR, seg);
            int w9 = wb + ii * 9;
            cacc(r0, H2u(wts2[w9+0]), H2u(wts2[w9+1]), H2u(wts2[w9+2]), o);
            cacc(r1, H2u(wts2[w9+3]), H2u(wts2[w9+4]), H2u(wts2[w9+5]), o);
            cacc(r2, H2u(wts2[w9+6]), H2u(wts2[w9+7]), H2u(wts2[w9+8]), o);
        }
        float f[8];
        #pragma unroll
        for (int k = 0; k < 4; ++k) {
            f[2*k]   = fmaxf(__low2float(o[k]), 0.f);
            f[2*k+1] = fmaxf(__high2float(o[k]), 0.f);
        }
        int cc = kind ? (HIDC + g) : g;
        *(uint4*)(catb + (size_t)cc * NPIX + row * NW + seg * 8) = pack8(f);
    }
}

// ================= MFMA GEMM for 1x1 convs =================
// OFMT: 0 = f32 out, 1 = bf16 out, 2 = fp16 out
template <typename TOut, bool RES, int OFMT>
__global__ __launch_bounds__(256) void gemm1x1_kernel(
    const u16* __restrict__ Bm, const float* __restrict__ Am,
    const float* __restrict__ res, TOut* __restrict__ Cm,
    int M, int K, size_t strideB, size_t strideC) {
    __shared__ u16 Ash[64 * 40];
    __shared__ u16 Bsh[128 * 40];
    const u16* Bz = Bm + (size_t)blockIdx.z * strideB;
    int n0 = blockIdx.x * 128;
    int m0 = blockIdx.y * 64;
    int tid = threadIdx.x;
    int w = tid >> 6, l15 = tid & 15, q = (tid & 63) >> 4;
    int amm = tid >> 2, akc = (tid & 3) * 8;
    int bkk = tid >> 3, bs0 = tid & 7;

    ffrag acc[8];
    #pragma unroll
    for (int nt = 0; nt < 8; ++nt)
        #pragma unroll
        for (int e = 0; e < 4; ++e) acc[nt][e] = 0.f;

    for (int k0 = 0; k0 < K; k0 += 32) {
        {
            int gm = m0 + amm;
            float f[8];
            #pragma unroll
            for (int e = 0; e < 8; ++e) {
                int gk = k0 + akc + e;
                f[e] = (gm < M && gk < K) ? Am[(size_t)gm * K + gk] : 0.f;
            }
            u32* dst = (u32*)&Ash[amm * 40 + akc];
            #pragma unroll
            for (int e = 0; e < 4; ++e) dst[e] = packbf(f[2 * e], f[2 * e + 1]);
        }
        {
            int gk = k0 + bkk;
            bool ok = gk < K;
            const u16* src = Bz + (size_t)gk * NPIX + n0;
            #pragma unroll
            for (int pass = 0; pass < 2; ++pass) {
                int nn = (bs0 + pass * 8) * 8;
                if (ok) {
                    uint4 v = *(const uint4*)(src + nn);
                    Bsh[(nn + 0) * 40 + bkk] = (u16)(v.x & 0xffff);
                    Bsh[(nn + 1) * 40 + bkk] = (u16)(v.x >> 16);
                    Bsh[(nn + 2) * 40 + bkk] = (u16)(v.y & 0xffff);
                    Bsh[(nn + 3) * 40 + bkk] = (u16)(v.y >> 16);
                    Bsh[(nn + 4) * 40 + bkk] = (u16)(v.z & 0xffff);
                    Bsh[(nn + 5) * 40 + bkk] = (u16)(v.z >> 16);
                    Bsh[(nn + 6) * 40 + bkk] = (u16)(v.w & 0xffff);
                    Bsh[(nn + 7) * 40 + bkk] = (u16)(v.w >> 16);
                } else {
                    #pragma unroll
                    for (int e = 0; e < 8; ++e) Bsh[(nn + e) * 40 + bkk] = 0;
                }
            }
        }
        __syncthreads();
        bfrag af = *(const bfrag*)&Ash[(w * 16 + l15) * 40 + q * 8];
        #pragma unroll
        for (int nt = 0; nt < 8; ++nt) {
            bfrag bf = *(const bfrag*)&Bsh[(nt * 16 + l15) * 40 + q * 8];
            acc[nt] = __builtin_amdgcn_mfma_f32_16x16x32_bf16(af, bf, acc[nt], 0, 0, 0);
        }
        __syncthreads();
    }
    TOut* Cz = Cm + (size_t)blockIdx.z * strideC;
    const float* rz = res + (RES ? (size_t)blockIdx.z * strideC : 0);
    int mrow = m0 + w * 16 + q * 4;
    #pragma unroll
    for (int nt = 0; nt < 8; ++nt) {
        int col = n0 + nt * 16 + l15;
        #pragma unroll
        for (int r = 0; r < 4; ++r) {
            int row = mrow + r;
            if (row < M) {
                float v = acc[nt][r];
                if (RES) v += rz[(size_t)row * NPIX + col];
                if constexpr (OFMT == 0) {
                    ((float*)Cz)[(size_t)row * NPIX + col] = v;
                } else if constexpr (OFMT == 1) {
                    ((u16*)Cz)[(size_t)row * NPIX + col] = f2u16(v);
                } else {
                    __half hh = __float2half(v);
                    ((u16*)Cz)[(size_t)row * NPIX + col] = __builtin_bit_cast(u16, hh);
                }
            }
        }
    }
}

// ---------------- LayerNorm (fp32 in, bf16 out), channel-split blocks ----------------
__global__ __launch_bounds__(256) void ln_kernel(
    const float* __restrict__ x, const float* __restrict__ g,
    const float* __restrict__ bta, u16* __restrict__ out) {
    int blk = blockIdx.x;
    int b = blk >> 9;
    int p = ((blk & 511) << 5) + (threadIdx.x & 31);
    int cg = threadIdx.x >> 5;
    const float* xb = x + (size_t)b * NC * NPIX + p;
    float v[12]; float s = 0.f, s2 = 0.f;
    #pragma unroll
    for (int j = 0; j < 12; ++j) {
        float t = xb[(size_t)(cg * 12 + j) * NPIX];
        v[j] = t; s += t; s2 += t * t;
    }
    __shared__ float ss[8][32], qq[8][32], smu[32], sinv[32];
    ss[cg][threadIdx.x & 31] = s; qq[cg][threadIdx.x & 31] = s2;
    __syncthreads();
    if (threadIdx.x < 32) {
        float S = 0.f, Q = 0.f;
        #pragma unroll
        for (int k = 0; k < 8; ++k) { S += ss[k][threadIdx.x]; Q += qq[k][threadIdx.x]; }
        float mu = S * (1.f / NC);
        float var = Q * (1.f / NC) - mu * mu;
        smu[threadIdx.x] = mu; sinv[threadIdx.x] = rsqrtf(var + 1e-5f);
    }
    __syncthreads();
    float mu = smu[threadIdx.x & 31], inv = sinv[threadIdx.x & 31];
    u16* ob = out + (size_t)b * NC * NPIX + p;
    #pragma unroll
    for (int j = 0; j < 12; ++j) {
        int c = cg * 12 + j;
        ob[(size_t)c * NPIX] = f2u16((v[j] - mu) * inv * g[c] + bta[c]);
    }
}

// load a 1x10 window row (8 aligned + 2 halo) with zero padding (global memory)
__device__ __forceinline__ void load_row_zpad(const u16* ib, int iy, int x0, float a[10]) {
    if (iy < 0 || iy >= NW) {
        #pragma unroll
        for (int k = 0; k < 10; ++k) a[k] = 0.f;
        return;
    }
    const u16* rp = ib + iy * NW;
    uint4 v = *(const uint4*)(rp + x0);
    a[1]=bflo(v.x); a[2]=bfhi(v.x); a[3]=bflo(v.y); a[4]=bfhi(v.y);
    a[5]=bflo(v.z); a[6]=bfhi(v.z); a[7]=bflo(v.w); a[8]=bfhi(v.w);
    a[0] = (x0 > 0)   ? bfu(rp[x0 - 1]) : 0.f;
    a[9] = (x0 < 120) ? bfu(rp[x0 + 8]) : 0.f;
}

// ---------------- depthwise 3x3 (qkv), zero pad, 4 rows x 8 px/thread ----------------
template <bool RELU>
__global__ __launch_bounds__(256) void dwconv3x3_kernel(
    const u16* __restrict__ in, const float* __restrict__ w,
    u16* __restrict__ out, int CHN, int ICN, int idiv) {
    int id = blockIdx.x * 256 + threadIdx.x;   // 0..511
    int ty = id >> 4, tx = id & 15;
    int y0 = ty * 4, x0 = tx * 8;
    int b = blockIdx.y / CHN, oc = blockIdx.y % CHN;
    int ic = oc / idiv;
    const u16* ib = in + ((size_t)b * ICN + ic) * NPIX;
    float a[6][10];
    #pragma unroll
    for (int k = 0; k < 6; ++k) load_row_zpad(ib, y0 - 1 + k, x0, a[k]);
    const float* wr = w + (size_t)oc * 9;
    float w9[9];
    #pragma unroll
    for (int k = 0; k < 9; ++k) w9[k] = wr[k];
    u16* ob = out + ((size_t)b * CHN + oc) * NPIX + y0 * NW + x0;
    #pragma unroll
    for (int jr = 0; jr < 4; ++jr) {
        float o[8];
        #pragma unroll
        for (int j = 0; j < 8; ++j) {
            float s = 0.f;
            #pragma unroll
            for (int r = 0; r < 3; ++r)
                #pragma unroll
                for (int kx = 0; kx < 3; ++kx)
                    s += w9[r * 3 + kx] * a[jr + r][j + kx];
            o[j] = RELU ? fmaxf(s, 0.f) : s;
        }
        *(uint4*)(ob + jr * NW) = pack8(o);
    }
}

// ---------------- q/k row L2 norms -> reciprocal scales ----------------
__global__ __launch_bounds__(256) void qknorm_kernel(
    const u16* __restrict__ qkv2, float* __restrict__ scales) {
    int r = blockIdx.x;
    int b = r / 192, ch = r % 192;
    const u16* src = qkv2 + ((size_t)b * 288 + ch) * NPIX;
    float s = 0.f;
    for (int p = threadIdx.x * 8; p < NPIX; p += 2048) {
        uint4 v = *(const uint4*)(src + p);
        float f[8];
        f[0]=bflo(v.x); f[1]=bfhi(v.x); f[2]=bflo(v.y); f[3]=bfhi(v.y);
        f[4]=bflo(v.z); f[5]=bfhi(v.z); f[6]=bflo(v.w); f[7]=bfhi(v.w);
        #pragma unroll
        for (int k = 0; k < 8; ++k) s += f[k] * f[k];
    }
    #pragma unroll
    for (int off = 32; off > 0; off >>= 1) s += __shfl_down(s, off, 64);
    __shared__ float part[4];
    int wid = threadIdx.x >> 6;
    if ((threadIdx.x & 63) == 0) part[wid] = s;
    __syncthreads();
    if (threadIdx.x == 0) {
        float tot = part[0] + part[1] + part[2] + part[3];
        scales[r] = 1.f / fmaxf(sqrtf(tot), 1e-12f);
    }
}

// ---------------- raw attn dots, 4-way pixel split + atomicAdd ----------------
__global__ __launch_bounds__(256) void attn_kernel(
    const u16* __restrict__ qkv2, float* __restrict__ attn_raw) {
    int blk = blockIdx.y;  // ((b*NHD+h)*CHD+i)
    int slice = blockIdx.x;
    int i = blk % CHD; int h = (blk / CHD) % NHD; int b = blk / (CHD * NHD);
    const u16* q = qkv2 + ((size_t)b * 288 + h * CHD + i) * NPIX;
    const u16* k = qkv2 + ((size_t)b * 288 + 96 + h * CHD) * NPIX;
    float acc[CHD];
    #pragma unroll
    for (int j = 0; j < CHD; ++j) acc[j] = 0.f;
    int p0 = slice * 4096;
    #pragma unroll
    for (int it = 0; it < 2; ++it) {
        int p = p0 + it * 2048 + threadIdx.x * 8;
        uint4 qv = *(const uint4*)(q + p);
        float qf[8];
        qf[0]=bflo(qv.x); qf[1]=bfhi(qv.x); qf[2]=bflo(qv.y); qf[3]=bfhi(qv.y);
        qf[4]=bflo(qv.z); qf[5]=bfhi(qv.z); qf[6]=bflo(qv.w); qf[7]=bfhi(qv.w);
        #pragma unroll
        for (int j = 0; j < CHD; ++j) {
            uint4 kv = *(const uint4*)(k + (size_t)j * NPIX + p);
            float s = qf[0]*bflo(kv.x) + qf[1]*bfhi(kv.x) + qf[2]*bflo(kv.y) + qf[3]*bfhi(kv.y)
                    + qf[4]*bflo(kv.z) + qf[5]*bfhi(kv.z) + qf[6]*bflo(kv.w) + qf[7]*bfhi(kv.w);
            acc[j] += s;
        }
    }
    __shared__ float part[4][CHD];
    int wid = threadIdx.x >> 6, lane = threadIdx.x & 63;
    #pragma unroll
    for (int j = 0; j < CHD; ++j) {
        float v = acc[j];
        #pragma unroll
        for (int off = 32; off > 0; off >>= 1) v += __shfl_down(v, off, 64);
        if (lane == 0) part[wid][j] = v;
    }
    __syncthreads();
    if (threadIdx.x < CHD) {
        int j = threadIdx.x;
        float d = part[0][j] + part[1][j] + part[2][j] + part[3][j];
        atomicAdd(&attn_raw[(size_t)blk * CHD + j], d);
    }
}

// ---------------- STS: scale raw dots, thresholds, softmax mix ----------------
__global__ __launch_bounds__(256) void sts_kernel(
    const float* __restrict__ attn, const float* __restrict__ scl,
    const float* __restrict__ temp, const float* __restrict__ tw,
    const float* __restrict__ w1, const float* __restrict__ b1,
    const float* __restrict__ w2, const float* __restrict__ b2,
    float* __restrict__ attn_c) {
    int b = blockIdx.x;
    __shared__ float sat[NHD * CHD * CHD];
    __shared__ float avg[NHD];
    __shared__ float thr[4][NHD];
    for (int idx = threadIdx.x; idx < NHD * CHD * CHD; idx += 256) {
        int h = idx / (CHD * CHD); int r = idx % (CHD * CHD);
        int i = r / CHD, j = r % CHD;
        sat[idx] = attn[(size_t)b * NHD * CHD * CHD + idx]
                 * scl[b * 192 + h * CHD + i] * scl[b * 192 + 96 + h * CHD + j] * temp[h];
    }
    __syncthreads();
    if (threadIdx.x < NHD) {
        float s = 0.f;
        for (int t = 0; t < CHD * CHD; ++t) s += fabsf(sat[threadIdx.x * CHD * CHD + t]);
        avg[threadIdx.x] = s * (1.f / (CHD * CHD));
    }
    __syncthreads();
    if (threadIdx.x < 4) {
        int s = threadIdx.x;
        float t1[NHD];
        for (int hp = 0; hp < NHD; ++hp) {
            float u = b1[s * NHD + hp];
            for (int h = 0; h < NHD; ++h) u += avg[h] * w1[s * 64 + hp * NHD + h];
            t1[hp] = fmaxf(u, 0.f);
        }
        for (int hp = 0; hp < NHD; ++hp) {
            float u = b2[s * NHD + hp];
            for (int h = 0; h < NHD; ++h) u += t1[h] * w2[s * 64 + hp * NHD + h];
            float gg = 1.f / (1.f + expf(-u));
            thr[s][hp] = avg[hp] * gg;
        }
    }
    __syncthreads();
    if (threadIdx.x < NHD * CHD) {
        int h = threadIdx.x / CHD, i = threadIdx.x % CHD;
        const float* arow = sat + (h * CHD + i) * CHD;
        float acc[CHD];
        #pragma unroll
        for (int j = 0; j < CHD; ++j) acc[j] = 0.f;
        for (int s = 0; s < 4; ++s) {
            float comp[CHD]; float m = -1e30f;
            #pragma unroll
            for (int j = 0; j < CHD; ++j) {
                float a = arow[j];
                float sg = (a > 0.f) ? 1.f : ((a < 0.f) ? -1.f : 0.f);
                float c = sg * fmaxf(fabsf(a) - thr[s][h], 0.f);
                comp[j] = c; m = fmaxf(m, c);
            }
            float sum = 0.f;
            #pragma unroll
            for (int j = 0; j < CHD; ++j) { comp[j] = expf(comp[j] - m); sum += comp[j]; }
            float wts2v = tw[s] / sum;
            #pragma unroll
            for (int j = 0; j < CHD; ++j) acc[j] += wts2v * comp[j];
        }
        for (int j = 0; j < CHD; ++j)
            attn_c[(size_t)b * NHD * CHD * CHD + (h * CHD + i) * CHD + j] = acc[j];
    }
}

// ---------------- out = attn_c @ v, 4 px/thread, bf16 out ----------------
__global__ __launch_bounds__(256) void av_kernel(
    const float* __restrict__ attn_c, const u16* __restrict__ qkv2,
    u16* __restrict__ outv) {
    int p0 = (blockIdx.x * 256 + threadIdx.x) * 4;
    int bc = blockIdx.y;
    int b = bc / NC, hc = bc % NC; int h = hc / CHD, i = hc % CHD;
    const float* a = attn_c + ((size_t)(b * NHD + h) * CHD + i) * CHD;
    const u16* v = qkv2 + ((size_t)b * 288 + 192 + h * CHD) * NPIX;
    float av[CHD];
    #pragma unroll
    for (int j = 0; j < CHD; ++j) av[j] = a[j];
    float o[4] = {0.f, 0.f, 0.f, 0.f};
    #pragma unroll
    for (int j = 0; j < CHD; ++j) {
        uint2 t = *(const uint2*)(v + (size_t)j * NPIX + p0);
        o[0] += av[j] * bflo(t.x); o[1] += av[j] * bfhi(t.x);
        o[2] += av[j] * bflo(t.y); o[3] += av[j] * bfhi(t.y);
    }
    uint2 t; t.x = packbf(o[0], o[1]); t.y = packbf(o[2], o[3]);
    *(uint2*)(outv + ((size_t)b * NC + hc) * NPIX + p0) = t;
}

// ---------------- launch ----------------
extern "C" void kernel_launch(void* const* d_in, const int* in_sizes, int n_in,
                              void* d_out, int out_size, void* d_ws, size_t ws_size,
                              hipStream_t stream) {
    const float* x       = (const float*)d_in[0];
    const float* norm1_w = (const float*)d_in[1];
    const float* norm1_b = (const float*)d_in[2];
    const float* qkv_w   = (const float*)d_in[3];
    const float* qkv_dw  = (const float*)d_in[4];
    const float* proj_w  = (const float*)d_in[5];
    const float* temp    = (const float*)d_in[6];
    const float* thw     = (const float*)d_in[7];
    const float* aw1     = (const float*)d_in[8];
    const float* ab1     = (const float*)d_in[9];
    const float* aw2     = (const float*)d_in[10];
    const float* ab2     = (const float*)d_in[11];
    const float* norm2_w = (const float*)d_in[12];
    const float* norm2_b = (const float*)d_in[13];
    const float* in_w    = (const float*)d_in[14];
    const float* main_w  = (const float*)d_in[15];
    const float* lp_w    = (const float*)d_in[16];
    const float* hp_w    = (const float*)d_in[17];
    const float* ld_w    = (const float*)d_in[18];
    const float* hd_w    = (const float*)d_in[19];
    const float* out_w   = (const float*)d_in[20];
    float* out = (float*)d_out;

    // ---- workspace layout ----
    char* ws = (char*)d_ws;
    float* x1    = (float*)(ws + 0);            // 12,582,912 fp32 residual stream
    u16*   xnb   = (u16*)(ws + 12582912);       // 6,291,456  bf16 LN/attn-out
    u16*   qkv1  = (u16*)(ws + 18874368);       // 18,874,368 bf16 [2][288][NPIX]
    u16*   qkv2  = (u16*)(ws + 37748736);       // 18,874,368 bf16 [2][288][NPIX]
    float* scl   = (float*)(ws + 56623104);
    float* attn  = (float*)(ws + 56639488);
    float* attnc = (float*)(ws + 56655872);
    char*  F0    = ws + 56672256;
    const size_t S_full = 33423360;
    bool full = ws_size >= (size_t)56672256 + S_full;   // 90,095,616

    dim3 blk(256);
    // ---- attention half ----
    ln_kernel<<<dim3(NB * NPIX / 32), blk, 0, stream>>>(x, norm1_w, norm1_b, xnb);
    gemm1x1_kernel<u16, false, 1><<<dim3(128, 5, NB), blk, 0, stream>>>(
        xnb, qkv_w, nullptr, qkv1, 288, 96, (size_t)NC * NPIX, (size_t)288 * NPIX);
    dwconv3x3_kernel<false><<<dim3(2, NB * 288), blk, 0, stream>>>(
        qkv1, qkv_dw, qkv2, 288, 288, 1);
    qknorm_kernel<<<dim3(NB * 192), blk, 0, stream>>>(qkv2, scl);
    (void)hipMemsetAsync(attn, 0, (size_t)NB * NHD * CHD * CHD * sizeof(float), stream);
    attn_kernel<<<dim3(4, NB * NHD * CHD), blk, 0, stream>>>(qkv2, attn);
    sts_kernel<<<dim3(NB), blk, 0, stream>>>(attn, scl, temp, thw, aw1, ab1, aw2, ab2, attnc);
    av_kernel<<<dim3(16, NB * NC), blk, 0, stream>>>(attnc, qkv2, xnb);
    gemm1x1_kernel<float, true, 0><<<dim3(128, 2, NB), blk, 0, stream>>>(
        xnb, proj_w, x, x1, 96, 96, (size_t)NC * NPIX, (size_t)NC * NPIX);
    // ---- FFN half ----
    ln_kernel<<<dim3(NB * NPIX / 32), blk, 0, stream>>>(x1, norm2_w, norm2_b, xnb);
    if (full) {
        u16* yi  = qkv1;     // fp16, 33.4 MB spanning qkv1+qkv2 (dead now)
        u16* cat = (u16*)F0; // bf16
        gemm1x1_kernel<u16, false, 2><<<dim3(128, 8, NB), blk, 0, stream>>>(
            xnb, in_w, nullptr, yi, H2C, 96, (size_t)NC * NPIX, (size_t)H2C * NPIX);
        ffnmid_kernel<<<dim3(16, HIDC, NB), blk, 0, stream>>>(
            yi, main_w, lp_w, hp_w, ld_w, hd_w, cat);
        gemm1x1_kernel<float, true, 0><<<dim3(128, 2, NB), blk, 0, stream>>>(
            cat, out_w, x1, out, 96, H2C, (size_t)H2C * NPIX, (size_t)NC * NPIX);
    } else {
        for (int b = 0; b < NB; ++b) {
            u16* yi  = qkv1;
            u16* cat = qkv2;
            gemm1x1_kernel<u16, false, 2><<<dim3(128, 8, 1), blk, 0, stream>>>(
                xnb + (size_t)b * NC * NPIX, in_w, nullptr, yi, H2C, 96, 0, 0);
            ffnmid_kernel<<<dim3(16, HIDC, 1), blk, 0, stream>>>(
                yi, main_w, lp_w, hp_w, ld_w, hd_w, cat);
            gemm1x1_kernel<float, true, 0><<<dim3(128, 2, 1), blk, 0, stream>>>(
                cat, out_w, x1 + (size_t)b * NC * NPIX, out + (size_t)b * NC * NPIX,
                96, H2C, 0, 0);
        }
    }
}

// Round 12
// 473.011 us; speedup vs baseline: 1.0553x; 1.0088x over previous
//
#include <hip/hip_runtime.h>
#include <hip/hip_bf16.h>
#include <hip/hip_fp16.h>

// Problem constants
#define NB   2
#define NC   96
#define NW   128
#define NPIX 16384   // 128*128
#define NHD  8
#define CHD  12
#define HIDC 255
#define H2C  510
#define H4C  1020

typedef __hip_bfloat16 bf16;
typedef unsigned short u16;
typedef unsigned int   u32;
typedef __half2 h2t;

typedef __attribute__((ext_vector_type(8))) __bf16 bfrag;
typedef __attribute__((ext_vector_type(4))) float  ffrag;

__device__ __forceinline__ float bfu(u16 u)  { return __uint_as_float(((u32)u) << 16); }
__device__ __forceinline__ float bflo(u32 u) { return __uint_as_float(u << 16); }
__device__ __forceinline__ float bfhi(u32 u) { return __uint_as_float(u & 0xffff0000u); }
__device__ __forceinline__ u16 f2u16(float a) {
    bf16 x = __float2bfloat16(a); return *(u16*)&x;
}
__device__ __forceinline__ u32 packbf(float a, float b) {
    return (u32)f2u16(a) | ((u32)f2u16(b) << 16);
}
__device__ __forceinline__ uint4 pack8(const float o[8]) {
    uint4 r; r.x = packbf(o[0], o[1]); r.y = packbf(o[2], o[3]);
    r.z = packbf(o[4], o[5]); r.w = packbf(o[6], o[7]); return r;
}

// half2 bit helpers
__device__ __forceinline__ h2t H2u(u32 v) { return __builtin_bit_cast(h2t, v); }
__device__ __forceinline__ u32 U32h(h2t v) { return __builtin_bit_cast(u32, v); }
// (lo.hi, hi.lo) pair — compiler lowers to v_alignbit
__device__ __forceinline__ u32 abit(u32 hi, u32 lo) { return (lo >> 16) | (hi << 16); }
// branch-free per-lane fp16 relu (sign bit set -> 0)
__device__ __forceinline__ h2t relu2(h2t v) {
    u32 u = U32h(v);
    u32 lo = (u & 0x8000u)     ? 0u : (u & 0xFFFFu);
    u32 hi = (u & 0x80000000u) ? 0u : (u & 0xFFFF0000u);
    return H2u(lo | hi);
}

// ---- LDS row layout: [8-u16 halo chunk][128 data], stride LSTR=136 u16.
// Left halo (col -1) at idx 7; right halo (col 128) at idx 136 (next row's chunk-0
// word-0). Window read = 1 ds_read_b128 (center) + 1 ds_read2_b32 (halo dwords at
// const offsets 3 & 8 off the same base) — was 3 b128 in R10 (48B for 20B used).
#define LSTR 136

// packed row window: 4 center pairs + 5 shifted pairs
struct Row { h2t c0, c1, c2, c3, l0, l1, l2, l3, l4; };
__device__ __forceinline__ Row loadrow(const u16* rb, int seg) {
    const u32* base = (const u32*)(rb + seg * 8);
    uint4 v = *(const uint4*)(base + 4);   // center chunk (16B aligned)
    u32 lo = base[3];                      // dword holding left-halo u16 (high half)
    u32 hi = base[8];                      // dword holding right-halo u16 (low half)
    Row r;
    r.c0 = H2u(v.x); r.c1 = H2u(v.y); r.c2 = H2u(v.z); r.c3 = H2u(v.w);
    r.l0 = H2u(abit(v.x, lo)); r.l1 = H2u(abit(v.y, v.x)); r.l2 = H2u(abit(v.z, v.y));
    r.l3 = H2u(abit(v.w, v.z)); r.l4 = H2u(abit(hi, v.w));
    return r;
}
// raw dwords of a row window (for box filter vertical sums incl. halo cols)
struct Raw { u32 w0; uint4 v; u32 r0; };
__device__ __forceinline__ Raw ldraw(const u16* rb, int seg) {
    const u32* base = (const u32*)(rb + seg * 8);
    Raw r;
    r.v  = *(const uint4*)(base + 4);
    r.w0 = base[3];
    r.r0 = base[8];
    return r;
}
// 3-tap horizontal conv accumulate: 12 pk-fma
__device__ __forceinline__ void cacc(const Row& r, h2t w0, h2t w1, h2t w2, h2t o[4]) {
    o[0] = __hfma2(w0, r.l0, __hfma2(w1, r.c0, __hfma2(w2, r.l1, o[0])));
    o[1] = __hfma2(w0, r.l1, __hfma2(w1, r.c1, __hfma2(w2, r.l2, o[1])));
    o[2] = __hfma2(w0, r.l2, __hfma2(w1, r.c2, __hfma2(w2, r.l3, o[2])));
    o[3] = __hfma2(w0, r.l3, __hfma2(w1, r.c3, __hfma2(w2, r.l4, o[3])));
}

// ================= fused FFN midsection (fp16 packed math) =================
// yi(fp16) --main dw+relu--> ym --box(replicate)--> l, hb=ym-l --lp/hp dw+relu-->
// lp,hp --ld/hd(4->1)+relu--> cat(bf16). Block = (8-row tile, group g, batch).
__global__ __launch_bounds__(256) void ffnmid_kernel(
    const u16* __restrict__ yi, const float* __restrict__ main_w,
    const float* __restrict__ lp_w, const float* __restrict__ hp_w,
    const float* __restrict__ ld_w, const float* __restrict__ hd_w,
    u16* __restrict__ cat) {
    const int oLPS = 0;       // [4][10][LSTR]+8 = 5448
    const int oHPS = 5448;    // -> 10896
    const int oYIS = 0;       // [2][16][LSTR]+8 = 4360 (dead after S2)
    const int oYMS = 10896;   // [4][14][LSTR]+8 = 7624 -> 18520
    const int oLLS = 18520;   // [4][12][LSTR]+8 = 6536 -> 25056
    const int oHBS = 25056;   // [4][12][LSTR]+8 = 6536 -> 31592
    __shared__ __align__(16) u16 lds[31600];
    __shared__ u32 wts2[180];  // duplicated-fp16 weights [main 36][lp 36][hp 36][ld 36][hd 36]

    int g  = blockIdx.y;
    int y0 = blockIdx.x * 8;
    int tid = threadIdx.x;
    const u16* yib = yi + (size_t)blockIdx.z * H2C * NPIX;
    u16* catb = cat + (size_t)blockIdx.z * H2C * NPIX;

    if (tid < 180) {
        int idx = tid; float v;
        if (idx < 36)       v = main_w[(4 * g) * 9 + idx];
        else if (idx < 72)  v = lp_w[(4 * g) * 9 + (idx - 36)];
        else if (idx < 108) v = hp_w[(4 * g) * 9 + (idx - 72)];
        else if (idx < 144) v = ld_w[g * 36 + (idx - 108)];
        else                v = hd_w[g * 36 + (idx - 144)];
        __half hh = __float2half(v);
        u16 hb16 = __builtin_bit_cast(u16, hh);
        wts2[idx] = (u32)hb16 * 0x10001u;
    }
    {
        u32* z = (u32*)&lds[oYIS];
        #pragma unroll
        for (int k = 0; k < 9; ++k) {
            int i = tid + k * 256;
            if (i < 2180) z[i] = 0;
        }
    }
    __syncthreads();
    // ---- S1: stage yi (fp16, 2 ch x 16 rows, image rows y0-4..y0+11, zero-pad) ----
    #pragma unroll
    for (int k = 0; k < 2; ++k) {
        int t = tid + k * 256;
        int seg = t & 15, s = (t >> 4) & 15, lc = t >> 8;
        int row = y0 - 4 + s;
        if ((unsigned)row < 128u) {
            uint4 v = *(const uint4*)(yib + (size_t)(2 * g + lc) * NPIX + row * NW + seg * 8);
            *(uint4*)&lds[oYIS + (lc * 16 + s) * LSTR + 8 + seg * 8] = v;
        }
    }
    __syncthreads();
    h2t z2 = H2u(0u);
    // ---- S2: ym = relu(main conv, zero pad); replicate col halos ----
    for (int t = tid; t < 896; t += 256) {
        int seg = t & 15; int u = t >> 4; int s = u % 14, ii = u / 14;
        int row = y0 - 3 + s;
        if ((unsigned)row >= 128u) continue;  // out-of-image ym rows never read
        int lc = ii >> 1;
        const u16* yb = &lds[oYIS + (lc * 16 + s) * LSTR];
        Row r0 = loadrow(yb, seg), r1 = loadrow(yb + LSTR, seg), r2 = loadrow(yb + 2 * LSTR, seg);
        h2t o[4] = {z2, z2, z2, z2};
        cacc(r0, H2u(wts2[ii*9+0]), H2u(wts2[ii*9+1]), H2u(wts2[ii*9+2]), o);
        cacc(r1, H2u(wts2[ii*9+3]), H2u(wts2[ii*9+4]), H2u(wts2[ii*9+5]), o);
        cacc(r2, H2u(wts2[ii*9+6]), H2u(wts2[ii*9+7]), H2u(wts2[ii*9+8]), o);
        #pragma unroll
        for (int k = 0; k < 4; ++k) o[k] = relu2(o[k]);
        u16* ymr = &lds[oYMS + (ii * 14 + s) * LSTR];
        uint4 st; st.x = U32h(o[0]); st.y = U32h(o[1]); st.z = U32h(o[2]); st.w = U32h(o[3]);
        *(uint4*)(ymr + 8 + seg * 8) = st;
        if (seg == 0)  ymr[7]   = (u16)(st.x & 0xffff);   // replicate left halo
        if (seg == 15) ymr[136] = (u16)(st.w >> 16);      // replicate right halo
    }
    __syncthreads();
    // ---- S3: l = box3x3(ym) replicate pad; hb = ym - l; zero outside image ----
    for (int t = tid; t < 768; t += 256) {
        int seg = t & 15; int u = t >> 4; int s = u % 12, ii = u / 12;
        int row = y0 - 2 + s;
        u16* llr = &lds[oLLS + (ii * 12 + s) * LSTR];
        u16* hbr = &lds[oHBS + (ii * 12 + s) * LSTR];
        uint4 lst = make_uint4(0, 0, 0, 0), hst = make_uint4(0, 0, 0, 0);
        if ((unsigned)row < 128u) {
            int r0 = min(max(row - 1, 0), 127) - (y0 - 3);
            int r1 = row - (y0 - 3);
            int r2 = min(max(row + 1, 0), 127) - (y0 - 3);
            const u16* ymb = &lds[oYMS + (ii * 14) * LSTR];
            Raw A = ldraw(ymb + r0 * LSTR, seg);
            Raw B = ldraw(ymb + r1 * LSTR, seg);
            Raw C = ldraw(ymb + r2 * LSTR, seg);
            // vertical sums (pairs), incl. halo cols
            h2t sW = __hadd2(__hadd2(H2u(A.w0), H2u(B.w0)), H2u(C.w0));
            h2t sx = __hadd2(__hadd2(H2u(A.v.x), H2u(B.v.x)), H2u(C.v.x));
            h2t sy = __hadd2(__hadd2(H2u(A.v.y), H2u(B.v.y)), H2u(C.v.y));
            h2t sz = __hadd2(__hadd2(H2u(A.v.z), H2u(B.v.z)), H2u(C.v.z));
            h2t sw = __hadd2(__hadd2(H2u(A.v.w), H2u(B.v.w)), H2u(C.v.w));
            h2t sR = __hadd2(__hadd2(H2u(A.r0), H2u(B.r0)), H2u(C.r0));
            u32 bW = U32h(sW), bx = U32h(sx), by = U32h(sy), bz = U32h(sz),
                bw = U32h(sw), bR = U32h(sR);
            h2t L0 = H2u(abit(bx, bW)), L1 = H2u(abit(by, bx)), L2 = H2u(abit(bz, by)),
                L3 = H2u(abit(bw, bz)), L4 = H2u(abit(bR, bw));
            __half k9h = __float2half(1.f / 9.f);
            h2t k9 = __halves2half2(k9h, k9h);
            h2t l0 = __hmul2(__hadd2(__hadd2(L0, sx), L1), k9);
            h2t l1 = __hmul2(__hadd2(__hadd2(L1, sy), L2), k9);
            h2t l2 = __hmul2(__hadd2(__hadd2(L2, sz), L3), k9);
            h2t l3 = __hmul2(__hadd2(__hadd2(L3, sw), L4), k9);
            h2t h0 = __hsub2(H2u(B.v.x), l0);
            h2t h1 = __hsub2(H2u(B.v.y), l1);
            h2t h2v = __hsub2(H2u(B.v.z), l2);
            h2t h3 = __hsub2(H2u(B.v.w), l3);
            lst.x = U32h(l0); lst.y = U32h(l1); lst.z = U32h(l2); lst.w = U32h(l3);
            hst.x = U32h(h0); hst.y = U32h(h1); hst.z = U32h(h2v); hst.w = U32h(h3);
        }
        *(uint4*)(llr + 8 + seg * 8) = lst;
        *(uint4*)(hbr + 8 + seg * 8) = hst;
        if (seg == 0)  { llr[7] = 0;   hbr[7] = 0; }
        if (seg == 15) { llr[136] = 0; hbr[136] = 0; }
    }
    __syncthreads();
    // ---- S4: lp = relu(conv(l)); hp = relu(conv(hb)) (zero pad) ----
    for (int t = tid; t < 1280; t += 256) {
        int kind = t >= 640;
        int r = t - (kind ? 640 : 0);
        int ii = r / 160; int rem = r - ii * 160;
        int s = rem >> 4, seg = rem & 15;
        int row = y0 - 1 + s;
        u16* dst = &lds[(kind ? oHPS : oLPS) + (ii * 10 + s) * LSTR];
        uint4 st = make_uint4(0, 0, 0, 0);
        if ((unsigned)row < 128u) {
            const u16* sb = &lds[(kind ? oHBS : oLLS) + (ii * 12 + s) * LSTR];
            Row r0 = loadrow(sb, seg), r1 = loadrow(sb + LSTR, seg), r2 = loadrow(sb + 2 * LSTR, seg);
            int wb = (kind ? 72 : 36) + ii * 9;
            h2t o[4] = {z2, z2, z2, z2};
            cacc(r0, H2u(wts2[wb+0]), H2u(wts2[wb+1]), H2u(wts2[wb+2]), o);
            cacc(r1, H2u(wts2[wb+3]), H2u(wts2[wb+4]), H2u(wts2[wb+5]), o);
            cacc(r2, H2u(wts2[wb+6]), H2u(wts2[wb+7]), H2u(wts2[wb+8]), o);
            #pragma unroll
            for (int k = 0; k < 4; ++k) o[k] = relu2(o[k]);
            st.x = U32h(o[0]); st.y = U32h(o[1]); st.z = U32h(o[2]); st.w = U32h(o[3]);
        }
        *(uint4*)(dst + 8 + seg * 8) = st;
        if (seg == 0)  dst[7]   = 0;
        if (seg == 15) dst[136] = 0;
    }
    __syncthreads();
    // ---- S5: ld & hd (4->1 grouped conv, zero pad) -> cat (bf16) ----
    {
        int kind = tid >> 7, s = (tid >> 4) & 7, seg = tid & 15;
        int row = y0 + s;
        int wb = kind ? 144 : 108;
        h2t o[4] = {z2, z2, z2, z2};
        #pragma unroll
        for (int ii = 0; ii < 4; ++ii) {
            int ch = 4 * g + ii;
            bool uselp = (ch < H2C) == (kind == 0);
            const u16* rb = &lds[(uselp ? oLPS : oHPS) + (ii * 10 + s) * LSTR];
            Row r0 = loadrow(rb, seg), r1 = loadrow(rb + LSTR, seg), r2 = loadrow(rb + 2 * LSTR, seg);
            int w9 = wb + ii * 9;
            cacc(r0, H2u(wts2[w9+0]), H2u(wts2[w9+1]), H2u(wts2[w9+2]), o);
            cacc(r1, H2u(wts2[w9+3]), H2u(wts2[w9+4]), H2u(wts2[w9+5]), o);
            cacc(r2, H2u(wts2[w9+6]), H2u(wts2[w9+7]), H2u(wts2[w9+8]), o);
        }
        float f[8];
        #pragma unroll
        for (int k = 0; k < 4; ++k) {
            f[2*k]   = fmaxf(__low2float(o[k]), 0.f);
            f[2*k+1] = fmaxf(__high2float(o[k]), 0.f);
        }
        int cc = kind ? (HIDC + g) : g;
        *(uint4*)(catb + (size_t)cc * NPIX + row * NW + seg * 8) = pack8(f);
    }
}

// ================= MFMA GEMM for 1x1 convs =================
// OFMT: 0 = f32 out, 1 = bf16 out, 2 = fp16 out
template <typename TOut, bool RES, int OFMT>
__global__ __launch_bounds__(256) void gemm1x1_kernel(
    const u16* __restrict__ Bm, const float* __restrict__ Am,
    const float* __restrict__ res, TOut* __restrict__ Cm,
    int M, int K, size_t strideB, size_t strideC) {
    __shared__ u16 Ash[64 * 40];
    __shared__ u16 Bsh[128 * 40];
    const u16* Bz = Bm + (size_t)blockIdx.z * strideB;
    int n0 = blockIdx.x * 128;
    int m0 = blockIdx.y * 64;
    int tid = threadIdx.x;
    int w = tid >> 6, l15 = tid & 15, q = (tid & 63) >> 4;
    int amm = tid >> 2, akc = (tid & 3) * 8;
    int bkk = tid >> 3, bs0 = tid & 7;

    ffrag acc[8];
    #pragma unroll
    for (int nt = 0; nt < 8; ++nt)
        #pragma unroll
        for (int e = 0; e < 4; ++e) acc[nt][e] = 0.f;

    for (int k0 = 0; k0 < K; k0 += 32) {
        {
            int gm = m0 + amm;
            float f[8];
            #pragma unroll
            for (int e = 0; e < 8; ++e) {
                int gk = k0 + akc + e;
                f[e] = (gm < M && gk < K) ? Am[(size_t)gm * K + gk] : 0.f;
            }
            u32* dst = (u32*)&Ash[amm * 40 + akc];
            #pragma unroll
            for (int e = 0; e < 4; ++e) dst[e] = packbf(f[2 * e], f[2 * e + 1]);
        }
        {
            int gk = k0 + bkk;
            bool ok = gk < K;
            const u16* src = Bz + (size_t)gk * NPIX + n0;
            #pragma unroll
            for (int pass = 0; pass < 2; ++pass) {
                int nn = (bs0 + pass * 8) * 8;
                if (ok) {
                    uint4 v = *(const uint4*)(src + nn);
                    Bsh[(nn + 0) * 40 + bkk] = (u16)(v.x & 0xffff);
                    Bsh[(nn + 1) * 40 + bkk] = (u16)(v.x >> 16);
                    Bsh[(nn + 2) * 40 + bkk] = (u16)(v.y & 0xffff);
                    Bsh[(nn + 3) * 40 + bkk] = (u16)(v.y >> 16);
                    Bsh[(nn + 4) * 40 + bkk] = (u16)(v.z & 0xffff);
                    Bsh[(nn + 5) * 40 + bkk] = (u16)(v.z >> 16);
                    Bsh[(nn + 6) * 40 + bkk] = (u16)(v.w & 0xffff);
                    Bsh[(nn + 7) * 40 + bkk] = (u16)(v.w >> 16);
                } else {
                    #pragma unroll
                    for (int e = 0; e < 8; ++e) Bsh[(nn + e) * 40 + bkk] = 0;
                }
            }
        }
        __syncthreads();
        bfrag af = *(const bfrag*)&Ash[(w * 16 + l15) * 40 + q * 8];
        #pragma unroll
        for (int nt = 0; nt < 8; ++nt) {
            bfrag bf = *(const bfrag*)&Bsh[(nt * 16 + l15) * 40 + q * 8];
            acc[nt] = __builtin_amdgcn_mfma_f32_16x16x32_bf16(af, bf, acc[nt], 0, 0, 0);
        }
        __syncthreads();
    }
    TOut* Cz = Cm + (size_t)blockIdx.z * strideC;
    const float* rz = res + (RES ? (size_t)blockIdx.z * strideC : 0);
    int mrow = m0 + w * 16 + q * 4;
    #pragma unroll
    for (int nt = 0; nt < 8; ++nt) {
        int col = n0 + nt * 16 + l15;
        #pragma unroll
        for (int r = 0; r < 4; ++r) {
            int row = mrow + r;
            if (row < M) {
                float v = acc[nt][r];
                if (RES) v += rz[(size_t)row * NPIX + col];
                if constexpr (OFMT == 0) {
                    ((float*)Cz)[(size_t)row * NPIX + col] = v;
                } else if constexpr (OFMT == 1) {
                    ((u16*)Cz)[(size_t)row * NPIX + col] = f2u16(v);
                } else {
                    __half hh = __float2half(v);
                    ((u16*)Cz)[(size_t)row * NPIX + col] = __builtin_bit_cast(u16, hh);
                }
            }
        }
    }
}

// ---------------- LayerNorm (fp32 in, bf16 out), channel-split blocks ----------------
__global__ __launch_bounds__(256) void ln_kernel(
    const float* __restrict__ x, const float* __restrict__ g,
    const float* __restrict__ bta, u16* __restrict__ out) {
    int blk = blockIdx.x;
    int b = blk >> 9;
    int p = ((blk & 511) << 5) + (threadIdx.x & 31);
    int cg = threadIdx.x >> 5;
    const float* xb = x + (size_t)b * NC * NPIX + p;
    float v[12]; float s = 0.f, s2 = 0.f;
    #pragma unroll
    for (int j = 0; j < 12; ++j) {
        float t = xb[(size_t)(cg * 12 + j) * NPIX];
        v[j] = t; s += t; s2 += t * t;
    }
    __shared__ float ss[8][32], qq[8][32], smu[32], sinv[32];
    ss[cg][threadIdx.x & 31] = s; qq[cg][threadIdx.x & 31] = s2;
    __syncthreads();
    if (threadIdx.x < 32) {
        float S = 0.f, Q = 0.f;
        #pragma unroll
        for (int k = 0; k < 8; ++k) { S += ss[k][threadIdx.x]; Q += qq[k][threadIdx.x]; }
        float mu = S * (1.f / NC);
        float var = Q * (1.f / NC) - mu * mu;
        smu[threadIdx.x] = mu; sinv[threadIdx.x] = rsqrtf(var + 1e-5f);
    }
    __syncthreads();
    float mu = smu[threadIdx.x & 31], inv = sinv[threadIdx.x & 31];
    u16* ob = out + (size_t)b * NC * NPIX + p;
    #pragma unroll
    for (int j = 0; j < 12; ++j) {
        int c = cg * 12 + j;
        ob[(size_t)c * NPIX] = f2u16((v[j] - mu) * inv * g[c] + bta[c]);
    }
}

// load a 1x10 window row (8 aligned + 2 halo) with zero padding (global memory)
__device__ __forceinline__ void load_row_zpad(const u16* ib, int iy, int x0, float a[10]) {
    if (iy < 0 || iy >= NW) {
        #pragma unroll
        for (int k = 0; k < 10; ++k) a[k] = 0.f;
        return;
    }
    const u16* rp = ib + iy * NW;
    uint4 v = *(const uint4*)(rp + x0);
    a[1]=bflo(v.x); a[2]=bfhi(v.x); a[3]=bflo(v.y); a[4]=bfhi(v.y);
    a[5]=bflo(v.z); a[6]=bfhi(v.z); a[7]=bflo(v.w); a[8]=bfhi(v.w);
    a[0] = (x0 > 0)   ? bfu(rp[x0 - 1]) : 0.f;
    a[9] = (x0 < 120) ? bfu(rp[x0 + 8]) : 0.f;
}

// ---------------- depthwise 3x3 (qkv), zero pad, 4 rows x 8 px/thread ----------------
template <bool RELU>
__global__ __launch_bounds__(256) void dwconv3x3_kernel(
    const u16* __restrict__ in, const float* __restrict__ w,
    u16* __restrict__ out, int CHN, int ICN, int idiv) {
    int id = blockIdx.x * 256 + threadIdx.x;   // 0..511
    int ty = id >> 4, tx = id & 15;
    int y0 = ty * 4, x0 = tx * 8;
    int b = blockIdx.y / CHN, oc = blockIdx.y % CHN;
    int ic = oc / idiv;
    const u16* ib = in + ((size_t)b * ICN + ic) * NPIX;
    float a[6][10];
    #pragma unroll
    for (int k = 0; k < 6; ++k) load_row_zpad(ib, y0 - 1 + k, x0, a[k]);
    const float* wr = w + (size_t)oc * 9;
    float w9[9];
    #pragma unroll
    for (int k = 0; k < 9; ++k) w9[k] = wr[k];
    u16* ob = out + ((size_t)b * CHN + oc) * NPIX + y0 * NW + x0;
    #pragma unroll
    for (int jr = 0; jr < 4; ++jr) {
        float o[8];
        #pragma unroll
        for (int j = 0; j < 8; ++j) {
            float s = 0.f;
            #pragma unroll
            for (int r = 0; r < 3; ++r)
                #pragma unroll
                for (int kx = 0; kx < 3; ++kx)
                    s += w9[r * 3 + kx] * a[jr + r][j + kx];
            o[j] = RELU ? fmaxf(s, 0.f) : s;
        }
        *(uint4*)(ob + jr * NW) = pack8(o);
    }
}

// ---------------- q/k row L2 norms -> reciprocal scales ----------------
__global__ __launch_bounds__(256) void qknorm_kernel(
    const u16* __restrict__ qkv2, float* __restrict__ scales) {
    int r = blockIdx.x;
    int b = r / 192, ch = r % 192;
    const u16* src = qkv2 + ((size_t)b * 288 + ch) * NPIX;
    float s = 0.f;
    for (int p = threadIdx.x * 8; p < NPIX; p += 2048) {
        uint4 v = *(const uint4*)(src + p);
        float f[8];
        f[0]=bflo(v.x); f[1]=bfhi(v.x); f[2]=bflo(v.y); f[3]=bfhi(v.y);
        f[4]=bflo(v.z); f[5]=bfhi(v.z); f[6]=bflo(v.w); f[7]=bfhi(v.w);
        #pragma unroll
        for (int k = 0; k < 8; ++k) s += f[k] * f[k];
    }
    #pragma unroll
    for (int off = 32; off > 0; off >>= 1) s += __shfl_down(s, off, 64);
    __shared__ float part[4];
    int wid = threadIdx.x >> 6;
    if ((threadIdx.x & 63) == 0) part[wid] = s;
    __syncthreads();
    if (threadIdx.x == 0) {
        float tot = part[0] + part[1] + part[2] + part[3];
        scales[r] = 1.f / fmaxf(sqrtf(tot), 1e-12f);
    }
}

// ---------------- raw attn dots, 4-way pixel split + atomicAdd ----------------
__global__ __launch_bounds__(256) void attn_kernel(
    const u16* __restrict__ qkv2, float* __restrict__ attn_raw) {
    int blk = blockIdx.y;  // ((b*NHD+h)*CHD+i)
    int slice = blockIdx.x;
    int i = blk % CHD; int h = (blk / CHD) % NHD; int b = blk / (CHD * NHD);
    const u16* q = qkv2 + ((size_t)b * 288 + h * CHD + i) * NPIX;
    const u16* k = qkv2 + ((size_t)b * 288 + 96 + h * CHD) * NPIX;
    float acc[CHD];
    #pragma unroll
    for (int j = 0; j < CHD; ++j) acc[j] = 0.f;
    int p0 = slice * 4096;
    #pragma unroll
    for (int it = 0; it < 2; ++it) {
        int p = p0 + it * 2048 + threadIdx.x * 8;
        uint4 qv = *(const uint4*)(q + p);
        float qf[8];
        qf[0]=bflo(qv.x); qf[1]=bfhi(qv.x); qf[2]=bflo(qv.y); qf[3]=bfhi(qv.y);
        qf[4]=bflo(qv.z); qf[5]=bfhi(qv.z); qf[6]=bflo(qv.w); qf[7]=bfhi(qv.w);
        #pragma unroll
        for (int j = 0; j < CHD; ++j) {
            uint4 kv = *(const uint4*)(k + (size_t)j * NPIX + p);
            float s = qf[0]*bflo(kv.x) + qf[1]*bfhi(kv.x) + qf[2]*bflo(kv.y) + qf[3]*bfhi(kv.y)
                    + qf[4]*bflo(kv.z) + qf[5]*bfhi(kv.z) + qf[6]*bflo(kv.w) + qf[7]*bfhi(kv.w);
            acc[j] += s;
        }
    }
    __shared__ float part[4][CHD];
    int wid = threadIdx.x >> 6, lane = threadIdx.x & 63;
    #pragma unroll
    for (int j = 0; j < CHD; ++j) {
        float v = acc[j];
        #pragma unroll
        for (int off = 32; off > 0; off >>= 1) v += __shfl_down(v, off, 64);
        if (lane == 0) part[wid][j] = v;
    }
    __syncthreads();
    if (threadIdx.x < CHD) {
        int j = threadIdx.x;
        float d = part[0][j] + part[1][j] + part[2][j] + part[3][j];
        atomicAdd(&attn_raw[(size_t)blk * CHD + j], d);
    }
}

// ---------------- STS: scale raw dots, thresholds, softmax mix ----------------
__global__ __launch_bounds__(256) void sts_kernel(
    const float* __restrict__ attn, const float* __restrict__ scl,
    const float* __restrict__ temp, const float* __restrict__ tw,
    const float* __restrict__ w1, const float* __restrict__ b1,
    const float* __restrict__ w2, const float* __restrict__ b2,
    float* __restrict__ attn_c) {
    int b = blockIdx.x;
    __shared__ float sat[NHD * CHD * CHD];
    __shared__ float avg[NHD];
    __shared__ float thr[4][NHD];
    for (int idx = threadIdx.x; idx < NHD * CHD * CHD; idx += 256) {
        int h = idx / (CHD * CHD); int r = idx % (CHD * CHD);
        int i = r / CHD, j = r % CHD;
        sat[idx] = attn[(size_t)b * NHD * CHD * CHD + idx]
                 * scl[b * 192 + h * CHD + i] * scl[b * 192 + 96 + h * CHD + j] * temp[h];
    }
    __syncthreads();
    if (threadIdx.x < NHD) {
        float s = 0.f;
        for (int t = 0; t < CHD * CHD; ++t) s += fabsf(sat[threadIdx.x * CHD * CHD + t]);
        avg[threadIdx.x] = s * (1.f / (CHD * CHD));
    }
    __syncthreads();
    if (threadIdx.x < 4) {
        int s = threadIdx.x;
        float t1[NHD];
        for (int hp = 0; hp < NHD; ++hp) {
            float u = b1[s * NHD + hp];
            for (int h = 0; h < NHD; ++h) u += avg[h] * w1[s * 64 + hp * NHD + h];
            t1[hp] = fmaxf(u, 0.f);
        }
        for (int hp = 0; hp < NHD; ++hp) {
            float u = b2[s * NHD + hp];
            for (int h = 0; h < NHD; ++h) u += t1[h] * w2[s * 64 + hp * NHD + h];
            float gg = 1.f / (1.f + expf(-u));
            thr[s][hp] = avg[hp] * gg;
        }
    }
    __syncthreads();
    if (threadIdx.x < NHD * CHD) {
        int h = threadIdx.x / CHD, i = threadIdx.x % CHD;
        const float* arow = sat + (h * CHD + i) * CHD;
        float acc[CHD];
        #pragma unroll
        for (int j = 0; j < CHD; ++j) acc[j] = 0.f;
        for (int s = 0; s < 4; ++s) {
            float comp[CHD]; float m = -1e30f;
            #pragma unroll
            for (int j = 0; j < CHD; ++j) {
                float a = arow[j];
                float sg = (a > 0.f) ? 1.f : ((a < 0.f) ? -1.f : 0.f);
                float c = sg * fmaxf(fabsf(a) - thr[s][h], 0.f);
                comp[j] = c; m = fmaxf(m, c);
            }
            float sum = 0.f;
            #pragma unroll
            for (int j = 0; j < CHD; ++j) { comp[j] = expf(comp[j] - m); sum += comp[j]; }
            float wts2v = tw[s] / sum;
            #pragma unroll
            for (int j = 0; j < CHD; ++j) acc[j] += wts2v * comp[j];
        }
        for (int j = 0; j < CHD; ++j)
            attn_c[(size_t)b * NHD * CHD * CHD + (h * CHD + i) * CHD + j] = acc[j];
    }
}

// ---------------- out = attn_c @ v, 4 px/thread, bf16 out ----------------
__global__ __launch_bounds__(256) void av_kernel(
    const float* __restrict__ attn_c, const u16* __restrict__ qkv2,
    u16* __restrict__ outv) {
    int p0 = (blockIdx.x * 256 + threadIdx.x) * 4;
    int bc = blockIdx.y;
    int b = bc / NC, hc = bc % NC; int h = hc / CHD, i = hc % CHD;
    const float* a = attn_c + ((size_t)(b * NHD + h) * CHD + i) * CHD;
    const u16* v = qkv2 + ((size_t)b * 288 + 192 + h * CHD) * NPIX;
    float av[CHD];
    #pragma unroll
    for (int j = 0; j < CHD; ++j) av[j] = a[j];
    float o[4] = {0.f, 0.f, 0.f, 0.f};
    #pragma unroll
    for (int j = 0; j < CHD; ++j) {
        uint2 t = *(const uint2*)(v + (size_t)j * NPIX + p0);
        o[0] += av[j] * bflo(t.x); o[1] += av[j] * bfhi(t.x);
        o[2] += av[j] * bflo(t.y); o[3] += av[j] * bfhi(t.y);
    }
    uint2 t; t.x = packbf(o[0], o[1]); t.y = packbf(o[2], o[3]);
    *(uint2*)(outv + ((size_t)b * NC + hc) * NPIX + p0) = t;
}

// ---------------- launch ----------------
extern "C" void kernel_launch(void* const* d_in, const int* in_sizes, int n_in,
                              void* d_out, int out_size, void* d_ws, size_t ws_size,
                              hipStream_t stream) {
    const float* x       = (const float*)d_in[0];
    const float* norm1_w = (const float*)d_in[1];
    const float* norm1_b = (const float*)d_in[2];
    const float* qkv_w   = (const float*)d_in[3];
    const float* qkv_dw  = (const float*)d_in[4];
    const float* proj_w  = (const float*)d_in[5];
    const float* temp    = (const float*)d_in[6];
    const float* thw     = (const float*)d_in[7];
    const float* aw1     = (const float*)d_in[8];
    const float* ab1     = (const float*)d_in[9];
    const float* aw2     = (const float*)d_in[10];
    const float* ab2     = (const float*)d_in[11];
    const float* norm2_w = (const float*)d_in[12];
    const float* norm2_b = (const float*)d_in[13];
    const float* in_w    = (const float*)d_in[14];
    const float* main_w  = (const float*)d_in[15];
    const float* lp_w    = (const float*)d_in[16];
    const float* hp_w    = (const float*)d_in[17];
    const float* ld_w    = (const float*)d_in[18];
    const float* hd_w    = (const float*)d_in[19];
    const float* out_w   = (const float*)d_in[20];
    float* out = (float*)d_out;

    // ---- workspace layout ----
    char* ws = (char*)d_ws;
    float* x1    = (float*)(ws + 0);            // 12,582,912 fp32 residual stream
    u16*   xnb   = (u16*)(ws + 12582912);       // 6,291,456  bf16 LN/attn-out
    u16*   qkv1  = (u16*)(ws + 18874368);       // 18,874,368 bf16 [2][288][NPIX]
    u16*   qkv2  = (u16*)(ws + 37748736);       // 18,874,368 bf16 [2][288][NPIX]
    float* scl   = (float*)(ws + 56623104);
    float* attn  = (float*)(ws + 56639488);
    float* attnc = (float*)(ws + 56655872);
    char*  F0    = ws + 56672256;
    const size_t S_full = 33423360;
    bool full = ws_size >= (size_t)56672256 + S_full;   // 90,095,616

    dim3 blk(256);
    // ---- attention half ----
    ln_kernel<<<dim3(NB * NPIX / 32), blk, 0, stream>>>(x, norm1_w, norm1_b, xnb);
    gemm1x1_kernel<u16, false, 1><<<dim3(128, 5, NB), blk, 0, stream>>>(
        xnb, qkv_w, nullptr, qkv1, 288, 96, (size_t)NC * NPIX, (size_t)288 * NPIX);
    dwconv3x3_kernel<false><<<dim3(2, NB * 288), blk, 0, stream>>>(
        qkv1, qkv_dw, qkv2, 288, 288, 1);
    qknorm_kernel<<<dim3(NB * 192), blk, 0, stream>>>(qkv2, scl);
    (void)hipMemsetAsync(attn, 0, (size_t)NB * NHD * CHD * CHD * sizeof(float), stream);
    attn_kernel<<<dim3(4, NB * NHD * CHD), blk, 0, stream>>>(qkv2, attn);
    sts_kernel<<<dim3(NB), blk, 0, stream>>>(attn, scl, temp, thw, aw1, ab1, aw2, ab2, attnc);
    av_kernel<<<dim3(16, NB * NC), blk, 0, stream>>>(attnc, qkv2, xnb);
    gemm1x1_kernel<float, true, 0><<<dim3(128, 2, NB), blk, 0, stream>>>(
        xnb, proj_w, x, x1, 96, 96, (size_t)NC * NPIX, (size_t)NC * NPIX);
    // ---- FFN half ----
    ln_kernel<<<dim3(NB * NPIX / 32), blk, 0, stream>>>(x1, norm2_w, norm2_b, xnb);
    if (full) {
        u16* yi  = qkv1;     // fp16, 33.4 MB spanning qkv1+qkv2 (dead now)
        u16* cat = (u16*)F0; // bf16
        gemm1x1_kernel<u16, false, 2><<<dim3(128, 8, NB), blk, 0, stream>>>(
            xnb, in_w, nullptr, yi, H2C, 96, (size_t)NC * NPIX, (size_t)H2C * NPIX);
        ffnmid_kernel<<<dim3(16, HIDC, NB), blk, 0, stream>>>(
            yi, main_w, lp_w, hp_w, ld_w, hd_w, cat);
        gemm1x1_kernel<float, true, 0><<<dim3(128, 2, NB), blk, 0, stream>>>(
            cat, out_w, x1, out, 96, H2C, (size_t)H2C * NPIX, (size_t)NC * NPIX);
    } else {
        for (int b = 0; b < NB; ++b) {
            u16* yi  = qkv1;
            u16* cat = qkv2;
            gemm1x1_kernel<u16, false, 2><<<dim3(128, 8, 1), blk, 0, stream>>>(
                xnb + (size_t)b * NC * NPIX, in_w, nullptr, yi, H2C, 96, 0, 0);
            ffnmid_kernel<<<dim3(16, HIDC, 1), blk, 0, stream>>>(
                yi, main_w, lp_w, hp_w, ld_w, hd_w, cat);
            gemm1x1_kernel<float, true, 0><<<dim3(128, 2, 1), blk, 0, stream>>>(
                cat, out_w, x1 + (size_t)b * NC * NPIX, out + (size_t)b * NC * NPIX,
                96, H2C, 0, 0);
        }
    }
}

// Round 13
// 363.376 us; speedup vs baseline: 1.3737x; 1.3017x over previous
//
#include <hip/hip_runtime.h>
#include <hip/hip_bf16.h>
#include <hip/hip_fp16.h>

// Problem constants
#define NB   2
#define NC   96
#define NW   128
#define NPIX 16384   // 128*128
#define NHD  8
#define CHD  12
#define HIDC 255
#define H2C  510
#define H4C  1020

typedef __hip_bfloat16 bf16;
typedef unsigned short u16;
typedef unsigned int   u32;
typedef __half2 h2t;

typedef __attribute__((ext_vector_type(8))) __bf16 bfrag;
typedef __attribute__((ext_vector_type(4))) float  ffrag;

__device__ __forceinline__ float bfu(u16 u)  { return __uint_as_float(((u32)u) << 16); }
__device__ __forceinline__ float bflo(u32 u) { return __uint_as_float(u << 16); }
__device__ __forceinline__ float bfhi(u32 u) { return __uint_as_float(u & 0xffff0000u); }
__device__ __forceinline__ u16 f2u16(float a) {
    bf16 x = __float2bfloat16(a); return *(u16*)&x;
}
__device__ __forceinline__ u32 packbf(float a, float b) {
    return (u32)f2u16(a) | ((u32)f2u16(b) << 16);
}
__device__ __forceinline__ uint4 pack8(const float o[8]) {
    uint4 r; r.x = packbf(o[0], o[1]); r.y = packbf(o[2], o[3]);
    r.z = packbf(o[4], o[5]); r.w = packbf(o[6], o[7]); return r;
}

// half2 bit helpers
__device__ __forceinline__ h2t H2u(u32 v) { return __builtin_bit_cast(h2t, v); }
__device__ __forceinline__ u32 U32h(h2t v) { return __builtin_bit_cast(u32, v); }
// branch-free per-lane fp16 relu (sign bit set -> 0)
__device__ __forceinline__ h2t relu2(h2t v) {
    u32 u = U32h(v);
    u32 lo = (u & 0x8000u)     ? 0u : (u & 0xFFFFu);
    u32 hi = (u & 0x80000000u) ? 0u : (u & 0xFFFF0000u);
    return H2u(lo | hi);
}
// splat low/high half of a packed fp16 pair (op_sel-foldable)
__device__ __forceinline__ h2t wtap(const h2t* a, int idx) {
    u32 u = U32h(a[idx >> 1]);
    u32 r = (idx & 1) ? ((u & 0xFFFF0000u) | (u >> 16)) : ((u << 16) | (u & 0xFFFFu));
    return H2u(r);
}

// ================= streaming FFN midsection =================
// One wave = (group g of 4 channels, 32-row strip, batch). Whole chain
// yi -> ym(dw,relu,zpad) -> box(replicate) l, hb=ym-l -> lp/hp(dw,relu,zpad)
// -> ld/hd(4->1,relu,zpad) -> cat, in a rolling register pipeline.
// Row = 128 px = 64 lanes x fp16 pair; horizontal halos via shuffles.
struct Trip { h2t L, C, R; };
__device__ __forceinline__ Trip shift3(h2t c2, bool repl, int lane) {
    u32 d = U32h(c2);
    u32 up = (u32)__shfl_up((int)d, 1);
    u32 dn = (u32)__shfl_down((int)d, 1);
    if (lane == 0)  up = repl ? (d << 16) : 0u;
    if (lane == 63) dn = repl ? (d >> 16) : 0u;
    Trip t; t.C = c2;
    t.L = H2u((up >> 16) | (d << 16));
    t.R = H2u((d >> 16) | (dn << 16));
    return t;
}
__device__ __forceinline__ h2t ldrow2(const u16* base, int row, int lane) {
    return ((unsigned)row < 128u) ? *(const h2t*)(base + row * NW + lane * 2) : H2u(0u);
}
// 3x3 conv contribution of one source row into 3 pending output rows
#define CONV3(W, c, T, Pa, Pb, Pc)                                             \
    Pc = __hfma2(wtap(W, (c)*9+0), T.L, __hfma2(wtap(W, (c)*9+1), T.C,         \
         __hfma2(wtap(W, (c)*9+2), T.R, Pc)));                                 \
    Pb = __hfma2(wtap(W, (c)*9+3), T.L, __hfma2(wtap(W, (c)*9+4), T.C,         \
         __hfma2(wtap(W, (c)*9+5), T.R, Pb)));                                 \
    Pa = __hfma2(wtap(W, (c)*9+6), T.L, __hfma2(wtap(W, (c)*9+7), T.C,         \
         __hfma2(wtap(W, (c)*9+8), T.R, Pa)));

__global__ __launch_bounds__(64) void ffnstream_kernel(
    const u16* __restrict__ yi, const float* __restrict__ main_w,
    const float* __restrict__ lp_w, const float* __restrict__ hp_w,
    const float* __restrict__ ld_w, const float* __restrict__ hd_w,
    u16* __restrict__ cat) {
    const int lane = threadIdx.x;
    const int g = blockIdx.y;
    const int R0 = blockIdx.x * 32, R1 = R0 + 32;
    const int L0 = max(R0 - 2, 0), L1 = min(R1 + 1, 127);
    const int P0 = max(R0 - 1, 0), P1 = min(R1, 127);
    const u16* yib = yi + (size_t)blockIdx.z * H2C * NPIX;
    u16* catb = cat + (size_t)blockIdx.z * H2C * NPIX;
    const u16* s0p = yib + (size_t)(2 * g) * NPIX;
    const u16* s1p = yib + (size_t)(2 * g + 1) * NPIX;

    // weights as packed fp16 pairs: tap j of channel c = index c*9+j
    h2t wm[18], wl[18], wh[18], wd[18], we[18];
    {
        const float* pm = main_w + 36 * g;
        const float* pl = lp_w + 36 * g;
        const float* ph = hp_w + 36 * g;
        const float* pd = ld_w + 36 * g;
        const float* pe = hd_w + 36 * g;
        #pragma unroll
        for (int k = 0; k < 18; ++k) {
            wm[k] = __halves2half2(__float2half(pm[2*k]), __float2half(pm[2*k+1]));
            wl[k] = __halves2half2(__float2half(pl[2*k]), __float2half(pl[2*k+1]));
            wh[k] = __halves2half2(__float2half(ph[2*k]), __float2half(ph[2*k+1]));
            wd[k] = __halves2half2(__float2half(pd[2*k]), __float2half(pd[2*k+1]));
            we[k] = __halves2half2(__float2half(pe[2*k]), __float2half(pe[2*k+1]));
        }
    }
    const h2t z = H2u(0u);
    const __half k9h = __float2half(1.f / 9.f);
    const h2t k9 = __halves2half2(k9h, k9h);

    h2t ymP0[4], ymP1[4], ymP2[4];     // pending ym rows yy-1, yy, yy+1
    h2t ymRa[4], ymRb[4], ymRc[4];     // completed ym rows yy-1, yy-2, yy-3
    h2t lpP0[4], lpP1[4], lpP2[4];
    h2t hpP0[4], hpP1[4], hpP2[4];
    h2t cd0 = z, cd1 = z, cd2 = z;     // pending cat(ld) rows yy-4, yy-3, yy-2
    h2t ce0 = z, ce1 = z, ce2 = z;     // pending cat(hd)
    #pragma unroll
    for (int c = 0; c < 4; ++c) {
        ymP0[c] = ymP1[c] = ymP2[c] = z;
        ymRa[c] = ymRb[c] = ymRc[c] = z;
        lpP0[c] = lpP1[c] = lpP2[c] = z;
        hpP0[c] = hpP1[c] = hpP2[c] = z;
    }

    const int ys = max(R0 - 3, 0) - 1;
    const int ye = R1 + 3;
    h2t cur0 = ldrow2(s0p, ys, lane), cur1 = ldrow2(s1p, ys, lane);
    for (int yy = ys; yy <= ye; ++yy) {
        h2t nxt0 = ldrow2(s0p, yy + 1, lane), nxt1 = ldrow2(s1p, yy + 1, lane);
        // A: ym contributions from yi row yy (zero-pad: OOR rows loaded as 0)
        {
            Trip t0 = shift3(cur0, false, lane);
            Trip t1 = shift3(cur1, false, lane);
            CONV3(wm, 0, t0, ymP0[0], ymP1[0], ymP2[0]);
            CONV3(wm, 1, t0, ymP0[1], ymP1[1], ymP2[1]);
            CONV3(wm, 2, t1, ymP0[2], ymP1[2], ymP2[2]);
            CONV3(wm, 3, t1, ymP0[3], ymP1[3], ymP2[3]);
        }
        // B: complete ym row yy-1 (relu); rotate ring & pendings
        #pragma unroll
        for (int c = 0; c < 4; ++c) {
            h2t n = relu2(ymP0[c]);
            ymRc[c] = ymRb[c]; ymRb[c] = ymRa[c]; ymRa[c] = n;
            ymP0[c] = ymP1[c]; ymP1[c] = ymP2[c]; ymP2[c] = z;
        }
        // C: l/hb row y_l = yy-2 (box replicate rows+cols); feed lp/hp pendings
        int y_l = yy - 2;
        if (y_l >= L0 && y_l <= L1) {
            #pragma unroll
            for (int c = 0; c < 4; ++c) {
                h2t top = (y_l == 0)   ? ymRb[c] : ymRc[c];
                h2t bot = (y_l == 127) ? ymRb[c] : ymRa[c];
                h2t vs = __hadd2(__hadd2(top, ymRb[c]), bot);
                Trip tv = shift3(vs, true, lane);
                h2t l  = __hmul2(__hadd2(__hadd2(tv.L, tv.C), tv.R), k9);
                h2t hb = __hsub2(ymRb[c], l);
                Trip tl = shift3(l, false, lane);
                CONV3(wl, c, tl, lpP0[c], lpP1[c], lpP2[c]);
                Trip th = shift3(hb, false, lane);
                CONV3(wh, c, th, hpP0[c], hpP1[c], hpP2[c]);
            }
        }
        // E: complete lp/hp row y_p = yy-3 (relu); feed ld/hd pendings
        int y_p = yy - 3;
        {
            h2t lpN[4], hpN[4];
            #pragma unroll
            for (int c = 0; c < 4; ++c) {
                lpN[c] = relu2(lpP0[c]); hpN[c] = relu2(hpP0[c]);
                lpP0[c] = lpP1[c]; lpP1[c] = lpP2[c]; lpP2[c] = z;
                hpP0[c] = hpP1[c]; hpP1[c] = hpP2[c]; hpP2[c] = z;
            }
            if (y_p >= P0 && y_p <= P1) {
                #pragma unroll
                for (int c = 0; c < 4; ++c) {
                    bool low = (4 * g + c) < H2C;
                    h2t sld = low ? lpN[c] : hpN[c];
                    h2t shd = low ? hpN[c] : lpN[c];
                    Trip ts = shift3(sld, false, lane);
                    CONV3(wd, c, ts, cd0, cd1, cd2);
                    Trip tu = shift3(shd, false, lane);
                    CONV3(we, c, tu, ce0, ce1, ce2);
                }
            }
        }
        // F: emit cat row y_c = yy-4 (relu, bf16)
        int y_c = yy - 4;
        if (y_c >= R0 && y_c < R1) {
            float a0 = fmaxf(__low2float(cd0), 0.f), a1 = fmaxf(__high2float(cd0), 0.f);
            float b0 = fmaxf(__low2float(ce0), 0.f), b1 = fmaxf(__high2float(ce0), 0.f);
            *(u32*)(catb + (size_t)g * NPIX + y_c * NW + lane * 2) = packbf(a0, a1);
            *(u32*)(catb + (size_t)(HIDC + g) * NPIX + y_c * NW + lane * 2) = packbf(b0, b1);
        }
        cd0 = cd1; cd1 = cd2; cd2 = z;
        ce0 = ce1; ce1 = ce2; ce2 = z;
        cur0 = nxt0; cur1 = nxt1;
    }
}

// ================= MFMA GEMM for 1x1 convs =================
// OFMT: 0 = f32 out, 1 = bf16 out, 2 = fp16 out
template <typename TOut, bool RES, int OFMT>
__global__ __launch_bounds__(256) void gemm1x1_kernel(
    const u16* __restrict__ Bm, const float* __restrict__ Am,
    const float* __restrict__ res, TOut* __restrict__ Cm,
    int M, int K, size_t strideB, size_t strideC) {
    __shared__ u16 Ash[64 * 40];
    __shared__ u16 Bsh[128 * 40];
    const u16* Bz = Bm + (size_t)blockIdx.z * strideB;
    int n0 = blockIdx.x * 128;
    int m0 = blockIdx.y * 64;
    int tid = threadIdx.x;
    int w = tid >> 6, l15 = tid & 15, q = (tid & 63) >> 4;
    int amm = tid >> 2, akc = (tid & 3) * 8;
    int bkk = tid >> 3, bs0 = tid & 7;

    ffrag acc[8];
    #pragma unroll
    for (int nt = 0; nt < 8; ++nt)
        #pragma unroll
        for (int e = 0; e < 4; ++e) acc[nt][e] = 0.f;

    for (int k0 = 0; k0 < K; k0 += 32) {
        {
            int gm = m0 + amm;
            float f[8];
            #pragma unroll
            for (int e = 0; e < 8; ++e) {
                int gk = k0 + akc + e;
                f[e] = (gm < M && gk < K) ? Am[(size_t)gm * K + gk] : 0.f;
            }
            u32* dst = (u32*)&Ash[amm * 40 + akc];
            #pragma unroll
            for (int e = 0; e < 4; ++e) dst[e] = packbf(f[2 * e], f[2 * e + 1]);
        }
        {
            int gk = k0 + bkk;
            bool ok = gk < K;
            const u16* src = Bz + (size_t)gk * NPIX + n0;
            #pragma unroll
            for (int pass = 0; pass < 2; ++pass) {
                int nn = (bs0 + pass * 8) * 8;
                if (ok) {
                    uint4 v = *(const uint4*)(src + nn);
                    Bsh[(nn + 0) * 40 + bkk] = (u16)(v.x & 0xffff);
                    Bsh[(nn + 1) * 40 + bkk] = (u16)(v.x >> 16);
                    Bsh[(nn + 2) * 40 + bkk] = (u16)(v.y & 0xffff);
                    Bsh[(nn + 3) * 40 + bkk] = (u16)(v.y >> 16);
                    Bsh[(nn + 4) * 40 + bkk] = (u16)(v.z & 0xffff);
                    Bsh[(nn + 5) * 40 + bkk] = (u16)(v.z >> 16);
                    Bsh[(nn + 6) * 40 + bkk] = (u16)(v.w & 0xffff);
                    Bsh[(nn + 7) * 40 + bkk] = (u16)(v.w >> 16);
                } else {
                    #pragma unroll
                    for (int e = 0; e < 8; ++e) Bsh[(nn + e) * 40 + bkk] = 0;
                }
            }
        }
        __syncthreads();
        bfrag af = *(const bfrag*)&Ash[(w * 16 + l15) * 40 + q * 8];
        #pragma unroll
        for (int nt = 0; nt < 8; ++nt) {
            bfrag bf = *(const bfrag*)&Bsh[(nt * 16 + l15) * 40 + q * 8];
            acc[nt] = __builtin_amdgcn_mfma_f32_16x16x32_bf16(af, bf, acc[nt], 0, 0, 0);
        }
        __syncthreads();
    }
    TOut* Cz = Cm + (size_t)blockIdx.z * strideC;
    const float* rz = res + (RES ? (size_t)blockIdx.z * strideC : 0);
    int mrow = m0 + w * 16 + q * 4;
    #pragma unroll
    for (int nt = 0; nt < 8; ++nt) {
        int col = n0 + nt * 16 + l15;
        #pragma unroll
        for (int r = 0; r < 4; ++r) {
            int row = mrow + r;
            if (row < M) {
                float v = acc[nt][r];
                if (RES) v += rz[(size_t)row * NPIX + col];
                if constexpr (OFMT == 0) {
                    ((float*)Cz)[(size_t)row * NPIX + col] = v;
                } else if constexpr (OFMT == 1) {
                    ((u16*)Cz)[(size_t)row * NPIX + col] = f2u16(v);
                } else {
                    __half hh = __float2half(v);
                    ((u16*)Cz)[(size_t)row * NPIX + col] = __builtin_bit_cast(u16, hh);
                }
            }
        }
    }
}

// ---------------- LayerNorm (fp32 in, bf16 out), channel-split blocks ----------------
__global__ __launch_bounds__(256) void ln_kernel(
    const float* __restrict__ x, const float* __restrict__ g,
    const float* __restrict__ bta, u16* __restrict__ out) {
    int blk = blockIdx.x;
    int b = blk >> 9;
    int p = ((blk & 511) << 5) + (threadIdx.x & 31);
    int cg = threadIdx.x >> 5;
    const float* xb = x + (size_t)b * NC * NPIX + p;
    float v[12]; float s = 0.f, s2 = 0.f;
    #pragma unroll
    for (int j = 0; j < 12; ++j) {
        float t = xb[(size_t)(cg * 12 + j) * NPIX];
        v[j] = t; s += t; s2 += t * t;
    }
    __shared__ float ss[8][32], qq[8][32], smu[32], sinv[32];
    ss[cg][threadIdx.x & 31] = s; qq[cg][threadIdx.x & 31] = s2;
    __syncthreads();
    if (threadIdx.x < 32) {
        float S = 0.f, Q = 0.f;
        #pragma unroll
        for (int k = 0; k < 8; ++k) { S += ss[k][threadIdx.x]; Q += qq[k][threadIdx.x]; }
        float mu = S * (1.f / NC);
        float var = Q * (1.f / NC) - mu * mu;
        smu[threadIdx.x] = mu; sinv[threadIdx.x] = rsqrtf(var + 1e-5f);
    }
    __syncthreads();
    float mu = smu[threadIdx.x & 31], inv = sinv[threadIdx.x & 31];
    u16* ob = out + (size_t)b * NC * NPIX + p;
    #pragma unroll
    for (int j = 0; j < 12; ++j) {
        int c = cg * 12 + j;
        ob[(size_t)c * NPIX] = f2u16((v[j] - mu) * inv * g[c] + bta[c]);
    }
}

// load a 1x10 window row (8 aligned + 2 halo) with zero padding (global memory)
__device__ __forceinline__ void load_row_zpad(const u16* ib, int iy, int x0, float a[10]) {
    if (iy < 0 || iy >= NW) {
        #pragma unroll
        for (int k = 0; k < 10; ++k) a[k] = 0.f;
        return;
    }
    const u16* rp = ib + iy * NW;
    uint4 v = *(const uint4*)(rp + x0);
    a[1]=bflo(v.x); a[2]=bfhi(v.x); a[3]=bflo(v.y); a[4]=bfhi(v.y);
    a[5]=bflo(v.z); a[6]=bfhi(v.z); a[7]=bflo(v.w); a[8]=bfhi(v.w);
    a[0] = (x0 > 0)   ? bfu(rp[x0 - 1]) : 0.f;
    a[9] = (x0 < 120) ? bfu(rp[x0 + 8]) : 0.f;
}

// ---------------- depthwise 3x3 (qkv), zero pad, 4 rows x 8 px/thread ----------------
template <bool RELU>
__global__ __launch_bounds__(256) void dwconv3x3_kernel(
    const u16* __restrict__ in, const float* __restrict__ w,
    u16* __restrict__ out, int CHN, int ICN, int idiv) {
    int id = blockIdx.x * 256 + threadIdx.x;   // 0..511
    int ty = id >> 4, tx = id & 15;
    int y0 = ty * 4, x0 = tx * 8;
    int b = blockIdx.y / CHN, oc = blockIdx.y % CHN;
    int ic = oc / idiv;
    const u16* ib = in + ((size_t)b * ICN + ic) * NPIX;
    float a[6][10];
    #pragma unroll
    for (int k = 0; k < 6; ++k) load_row_zpad(ib, y0 - 1 + k, x0, a[k]);
    const float* wr = w + (size_t)oc * 9;
    float w9[9];
    #pragma unroll
    for (int k = 0; k < 9; ++k) w9[k] = wr[k];
    u16* ob = out + ((size_t)b * CHN + oc) * NPIX + y0 * NW + x0;
    #pragma unroll
    for (int jr = 0; jr < 4; ++jr) {
        float o[8];
        #pragma unroll
        for (int j = 0; j < 8; ++j) {
            float s = 0.f;
            #pragma unroll
            for (int r = 0; r < 3; ++r)
                #pragma unroll
                for (int kx = 0; kx < 3; ++kx)
                    s += w9[r * 3 + kx] * a[jr + r][j + kx];
            o[j] = RELU ? fmaxf(s, 0.f) : s;
        }
        *(uint4*)(ob + jr * NW) = pack8(o);
    }
}

// ---------------- q/k row L2 norms -> reciprocal scales ----------------
__global__ __launch_bounds__(256) void qknorm_kernel(
    const u16* __restrict__ qkv2, float* __restrict__ scales) {
    int r = blockIdx.x;
    int b = r / 192, ch = r % 192;
    const u16* src = qkv2 + ((size_t)b * 288 + ch) * NPIX;
    float s = 0.f;
    for (int p = threadIdx.x * 8; p < NPIX; p += 2048) {
        uint4 v = *(const uint4*)(src + p);
        float f[8];
        f[0]=bflo(v.x); f[1]=bfhi(v.x); f[2]=bflo(v.y); f[3]=bfhi(v.y);
        f[4]=bflo(v.z); f[5]=bfhi(v.z); f[6]=bflo(v.w); f[7]=bfhi(v.w);
        #pragma unroll
        for (int k = 0; k < 8; ++k) s += f[k] * f[k];
    }
    #pragma unroll
    for (int off = 32; off > 0; off >>= 1) s += __shfl_down(s, off, 64);
    __shared__ float part[4];
    int wid = threadIdx.x >> 6;
    if ((threadIdx.x & 63) == 0) part[wid] = s;
    __syncthreads();
    if (threadIdx.x == 0) {
        float tot = part[0] + part[1] + part[2] + part[3];
        scales[r] = 1.f / fmaxf(sqrtf(tot), 1e-12f);
    }
}

// ---------------- raw attn dots, 4-way pixel split + atomicAdd ----------------
__global__ __launch_bounds__(256) void attn_kernel(
    const u16* __restrict__ qkv2, float* __restrict__ attn_raw) {
    int blk = blockIdx.y;  // ((b*NHD+h)*CHD+i)
    int slice = blockIdx.x;
    int i = blk % CHD; int h = (blk / CHD) % NHD; int b = blk / (CHD * NHD);
    const u16* q = qkv2 + ((size_t)b * 288 + h * CHD + i) * NPIX;
    const u16* k = qkv2 + ((size_t)b * 288 + 96 + h * CHD) * NPIX;
    float acc[CHD];
    #pragma unroll
    for (int j = 0; j < CHD; ++j) acc[j] = 0.f;
    int p0 = slice * 4096;
    #pragma unroll
    for (int it = 0; it < 2; ++it) {
        int p = p0 + it * 2048 + threadIdx.x * 8;
        uint4 qv = *(const uint4*)(q + p);
        float qf[8];
        qf[0]=bflo(qv.x); qf[1]=bfhi(qv.x); qf[2]=bflo(qv.y); qf[3]=bfhi(qv.y);
        qf[4]=bflo(qv.z); qf[5]=bfhi(qv.z); qf[6]=bflo(qv.w); qf[7]=bfhi(qv.w);
        #pragma unroll
        for (int j = 0; j < CHD; ++j) {
            uint4 kv = *(const uint4*)(k + (size_t)j * NPIX + p);
            float s = qf[0]*bflo(kv.x) + qf[1]*bfhi(kv.x) + qf[2]*bflo(kv.y) + qf[3]*bfhi(kv.y)
                    + qf[4]*bflo(kv.z) + qf[5]*bfhi(kv.z) + qf[6]*bflo(kv.w) + qf[7]*bfhi(kv.w);
            acc[j] += s;
        }
    }
    __shared__ float part[4][CHD];
    int wid = threadIdx.x >> 6, lane = threadIdx.x & 63;
    #pragma unroll
    for (int j = 0; j < CHD; ++j) {
        float v = acc[j];
        #pragma unroll
        for (int off = 32; off > 0; off >>= 1) v += __shfl_down(v, off, 64);
        if (lane == 0) part[wid][j] = v;
    }
    __syncthreads();
    if (threadIdx.x < CHD) {
        int j = threadIdx.x;
        float d = part[0][j] + part[1][j] + part[2][j] + part[3][j];
        atomicAdd(&attn_raw[(size_t)blk * CHD + j], d);
    }
}

// ---------------- STS: scale raw dots, thresholds, softmax mix ----------------
__global__ __launch_bounds__(256) void sts_kernel(
    const float* __restrict__ attn, const float* __restrict__ scl,
    const float* __restrict__ temp, const float* __restrict__ tw,
    const float* __restrict__ w1, const float* __restrict__ b1,
    const float* __restrict__ w2, const float* __restrict__ b2,
    float* __restrict__ attn_c) {
    int b = blockIdx.x;
    __shared__ float sat[NHD * CHD * CHD];
    __shared__ float avg[NHD];
    __shared__ float thr[4][NHD];
    for (int idx = threadIdx.x; idx < NHD * CHD * CHD; idx += 256) {
        int h = idx / (CHD * CHD); int r = idx % (CHD * CHD);
        int i = r / CHD, j = r % CHD;
        sat[idx] = attn[(size_t)b * NHD * CHD * CHD + idx]
                 * scl[b * 192 + h * CHD + i] * scl[b * 192 + 96 + h * CHD + j] * temp[h];
    }
    __syncthreads();
    if (threadIdx.x < NHD) {
        float s = 0.f;
        for (int t = 0; t < CHD * CHD; ++t) s += fabsf(sat[threadIdx.x * CHD * CHD + t]);
        avg[threadIdx.x] = s * (1.f / (CHD * CHD));
    }
    __syncthreads();
    if (threadIdx.x < 4) {
        int s = threadIdx.x;
        float t1[NHD];
        for (int hp = 0; hp < NHD; ++hp) {
            float u = b1[s * NHD + hp];
            for (int h = 0; h < NHD; ++h) u += avg[h] * w1[s * 64 + hp * NHD + h];
            t1[hp] = fmaxf(u, 0.f);
        }
        for (int hp = 0; hp < NHD; ++hp) {
            float u = b2[s * NHD + hp];
            for (int h = 0; h < NHD; ++h) u += t1[h] * w2[s * 64 + hp * NHD + h];
            float gg = 1.f / (1.f + expf(-u));
            thr[s][hp] = avg[hp] * gg;
        }
    }
    __syncthreads();
    if (threadIdx.x < NHD * CHD) {
        int h = threadIdx.x / CHD, i = threadIdx.x % CHD;
        const float* arow = sat + (h * CHD + i) * CHD;
        float acc[CHD];
        #pragma unroll
        for (int j = 0; j < CHD; ++j) acc[j] = 0.f;
        for (int s = 0; s < 4; ++s) {
            float comp[CHD]; float m = -1e30f;
            #pragma unroll
            for (int j = 0; j < CHD; ++j) {
                float a = arow[j];
                float sg = (a > 0.f) ? 1.f : ((a < 0.f) ? -1.f : 0.f);
                float c = sg * fmaxf(fabsf(a) - thr[s][h], 0.f);
                comp[j] = c; m = fmaxf(m, c);
            }
            float sum = 0.f;
            #pragma unroll
            for (int j = 0; j < CHD; ++j) { comp[j] = expf(comp[j] - m); sum += comp[j]; }
            float wts2v = tw[s] / sum;
            #pragma unroll
            for (int j = 0; j < CHD; ++j) acc[j] += wts2v * comp[j];
        }
        for (int j = 0; j < CHD; ++j)
            attn_c[(size_t)b * NHD * CHD * CHD + (h * CHD + i) * CHD + j] = acc[j];
    }
}

// ---------------- out = attn_c @ v, 4 px/thread, bf16 out ----------------
__global__ __launch_bounds__(256) void av_kernel(
    const float* __restrict__ attn_c, const u16* __restrict__ qkv2,
    u16* __restrict__ outv) {
    int p0 = (blockIdx.x * 256 + threadIdx.x) * 4;
    int bc = blockIdx.y;
    int b = bc / NC, hc = bc % NC; int h = hc / CHD, i = hc % CHD;
    const float* a = attn_c + ((size_t)(b * NHD + h) * CHD + i) * CHD;
    const u16* v = qkv2 + ((size_t)b * 288 + 192 + h * CHD) * NPIX;
    float av[CHD];
    #pragma unroll
    for (int j = 0; j < CHD; ++j) av[j] = a[j];
    float o[4] = {0.f, 0.f, 0.f, 0.f};
    #pragma unroll
    for (int j = 0; j < CHD; ++j) {
        uint2 t = *(const uint2*)(v + (size_t)j * NPIX + p0);
        o[0] += av[j] * bflo(t.x); o[1] += av[j] * bfhi(t.x);
        o[2] += av[j] * bflo(t.y); o[3] += av[j] * bfhi(t.y);
    }
    uint2 t; t.x = packbf(o[0], o[1]); t.y = packbf(o[2], o[3]);
    *(uint2*)(outv + ((size_t)b * NC + hc) * NPIX + p0) = t;
}

// ---------------- launch ----------------
extern "C" void kernel_launch(void* const* d_in, const int* in_sizes, int n_in,
                              void* d_out, int out_size, void* d_ws, size_t ws_size,
                              hipStream_t stream) {
    const float* x       = (const float*)d_in[0];
    const float* norm1_w = (const float*)d_in[1];
    const float* norm1_b = (const float*)d_in[2];
    const float* qkv_w   = (const float*)d_in[3];
    const float* qkv_dw  = (const float*)d_in[4];
    const float* proj_w  = (const float*)d_in[5];
    const float* temp    = (const float*)d_in[6];
    const float* thw     = (const float*)d_in[7];
    const float* aw1     = (const float*)d_in[8];
    const float* ab1     = (const float*)d_in[9];
    const float* aw2     = (const float*)d_in[10];
    const float* ab2     = (const float*)d_in[11];
    const float* norm2_w = (const float*)d_in[12];
    const float* norm2_b = (const float*)d_in[13];
    const float* in_w    = (const float*)d_in[14];
    const float* main_w  = (const float*)d_in[15];
    const float* lp_w    = (const float*)d_in[16];
    const float* hp_w    = (const float*)d_in[17];
    const float* ld_w    = (const float*)d_in[18];
    const float* hd_w    = (const float*)d_in[19];
    const float* out_w   = (const float*)d_in[20];
    float* out = (float*)d_out;

    // ---- workspace layout ----
    char* ws = (char*)d_ws;
    float* x1    = (float*)(ws + 0);            // 12,582,912 fp32 residual stream
    u16*   xnb   = (u16*)(ws + 12582912);       // 6,291,456  bf16 LN/attn-out
    u16*   qkv1  = (u16*)(ws + 18874368);       // 18,874,368 bf16 [2][288][NPIX]
    u16*   qkv2  = (u16*)(ws + 37748736);       // 18,874,368 bf16 [2][288][NPIX]
    float* scl   = (float*)(ws + 56623104);
    float* attn  = (float*)(ws + 56639488);
    float* attnc = (float*)(ws + 56655872);
    char*  F0    = ws + 56672256;
    const size_t S_full = 33423360;
    bool full = ws_size >= (size_t)56672256 + S_full;   // 90,095,616

    dim3 blk(256);
    // ---- attention half ----
    ln_kernel<<<dim3(NB * NPIX / 32), blk, 0, stream>>>(x, norm1_w, norm1_b, xnb);
    gemm1x1_kernel<u16, false, 1><<<dim3(128, 5, NB), blk, 0, stream>>>(
        xnb, qkv_w, nullptr, qkv1, 288, 96, (size_t)NC * NPIX, (size_t)288 * NPIX);
    dwconv3x3_kernel<false><<<dim3(2, NB * 288), blk, 0, stream>>>(
        qkv1, qkv_dw, qkv2, 288, 288, 1);
    qknorm_kernel<<<dim3(NB * 192), blk, 0, stream>>>(qkv2, scl);
    (void)hipMemsetAsync(attn, 0, (size_t)NB * NHD * CHD * CHD * sizeof(float), stream);
    attn_kernel<<<dim3(4, NB * NHD * CHD), blk, 0, stream>>>(qkv2, attn);
    sts_kernel<<<dim3(NB), blk, 0, stream>>>(attn, scl, temp, thw, aw1, ab1, aw2, ab2, attnc);
    av_kernel<<<dim3(16, NB * NC), blk, 0, stream>>>(attnc, qkv2, xnb);
    gemm1x1_kernel<float, true, 0><<<dim3(128, 2, NB), blk, 0, stream>>>(
        xnb, proj_w, x, x1, 96, 96, (size_t)NC * NPIX, (size_t)NC * NPIX);
    // ---- FFN half ----
    ln_kernel<<<dim3(NB * NPIX / 32), blk, 0, stream>>>(x1, norm2_w, norm2_b, xnb);
    if (full) {
        u16* yi  = qkv1;     // fp16, 33.4 MB spanning qkv1+qkv2 (dead now)
        u16* cat = (u16*)F0; // bf16
        gemm1x1_kernel<u16, false, 2><<<dim3(128, 8, NB), blk, 0, stream>>>(
            xnb, in_w, nullptr, yi, H2C, 96, (size_t)NC * NPIX, (size_t)H2C * NPIX);
        ffnstream_kernel<<<dim3(4, HIDC, NB), dim3(64), 0, stream>>>(
            yi, main_w, lp_w, hp_w, ld_w, hd_w, cat);
        gemm1x1_kernel<float, true, 0><<<dim3(128, 2, NB), blk, 0, stream>>>(
            cat, out_w, x1, out, 96, H2C, (size_t)H2C * NPIX, (size_t)NC * NPIX);
    } else {
        for (int b = 0; b < NB; ++b) {
            u16* yi  = qkv1;
            u16* cat = qkv2;
            gemm1x1_kernel<u16, false, 2><<<dim3(128, 8, 1), blk, 0, stream>>>(
                xnb + (size_t)b * NC * NPIX, in_w, nullptr, yi, H2C, 96, 0, 0);
            ffnstream_kernel<<<dim3(4, HIDC, 1), dim3(64), 0, stream>>>(
                yi, main_w, lp_w, hp_w, ld_w, hd_w, cat);
            gemm1x1_kernel<float, true, 0><<<dim3(128, 2, 1), blk, 0, stream>>>(
                cat, out_w, x1 + (size_t)b * NC * NPIX, out + (size_t)b * NC * NPIX,
                96, H2C, 0, 0);
        }
    }
}